// Round 5
// baseline (1121.910 us; speedup 1.0000x reference)
//
#include <hip/hip_runtime.h>
#include <hip/hip_bf16.h>
#include <math.h>

// ---------------- types / helpers ----------------
typedef __attribute__((ext_vector_type(8))) short bf16x8;
typedef __attribute__((ext_vector_type(4))) float f32x4;

#define DEV static __device__ __forceinline__
#define AS1 __attribute__((address_space(1)))
#define AS3 __attribute__((address_space(3)))

DEV float bf2f(__hip_bfloat16 v) { return __bfloat162float(v); }
DEV __hip_bfloat16 f2bf(float f) { return __float2bfloat16(f); }
DEV float us2f(unsigned short u) { return __uint_as_float(((unsigned int)u) << 16); }
DEV unsigned short f2us(float f) {
    __hip_bfloat16 b = __float2bfloat16(f);
    return *(unsigned short*)&b;
}

// async global->LDS, 16 B per lane (LDS dst = wave-uniform base + lane*16)
DEV void gload_lds16(const void* g, void* l) {
    __builtin_amdgcn_global_load_lds((const AS1 unsigned int*)g,
                                     (AS3 unsigned int*)l, 16, 0, 0);
}

// load 8 consecutive floats from an input tensor that is either f32 or bf16
DEV void load8(const void* p, size_t off, int f32m, float* o) {
    if (f32m) {
        const float4* r = (const float4*)((const float*)p + off);
        float4 A = r[0], B = r[1];
        o[0] = A.x; o[1] = A.y; o[2] = A.z; o[3] = A.w;
        o[4] = B.x; o[5] = B.y; o[6] = B.z; o[7] = B.w;
    } else {
        const ushort4* r = (const ushort4*)((const __hip_bfloat16*)p + off);
        ushort4 A = r[0], B = r[1];
        o[0] = us2f(A.x); o[1] = us2f(A.y); o[2] = us2f(A.z); o[3] = us2f(A.w);
        o[4] = us2f(B.x); o[5] = us2f(B.y); o[6] = us2f(B.z); o[7] = us2f(B.w);
    }
}

DEV float loadElem(const void* p, size_t idx, int f32m) {
    return f32m ? ((const float*)p)[idx] : bf2f(((const __hip_bfloat16*)p)[idx]);
}

// ---------------- problem constants ----------------
// B=8 S=8192 D=512 H=8 HK=2 DH=64 M=64 DFF=2048 NCLS=2 G=4
constexpr int NTOK = 65536;   // 8*8192

// ---------------- persistent ws layout (bytes) ----------------
constexpr size_t OFF_WQPT = 0;                       // bf16 [512][512]  (Wq@Wphi)^T
constexpr size_t OFF_WKPT = OFF_WQPT + 524288ull;    // bf16 [128][512]  (Wk@Wphi)^T   } contiguous:
constexpr size_t OFF_WVT  = OFF_WKPT + 131072ull;    // bf16 [128][512]  Wv^T          } [256][512]
constexpr size_t OFF_WOT  = OFF_WVT  + 131072ull;    // bf16 [512][512]  Wo^T
constexpr size_t OFF_WGT  = OFF_WOT  + 524288ull;    // bf16 [2048][512] Wg^T
constexpr size_t OFF_WUT  = OFF_WGT  + 2097152ull;   // bf16 [2048][512] Wu^T
constexpr size_t OFF_KV   = OFF_WUT  + 2097152ull;   // f32  [8][2][64][64]
constexpr size_t OFF_Z    = OFF_KV   + 262144ull;    // f32  [8][2][64]
constexpr size_t OFF_POOL = OFF_Z    + 4096ull;      // f32  [8][512]
constexpr size_t OFF_TSUM = OFF_POOL + 16384ull;     // f32  [8][2048]  col-sums of FFN t
constexpr size_t OFF_FLAG = OFF_TSUM + 65536ull;     // int  dtype flag (1 = f32 inputs)
constexpr size_t PERSIST  = OFF_FLAG + 256ull;
// h is persistent for ALL tokens (pass A writes, pass B reads then overwrites per-chunk)
constexpr size_t OFF_H    = PERSIST;                 // bf16 [65536][512] = 64 MB
constexpr size_t CHUNKBASE = OFF_H + 67108864ull;
constexpr int    ZERO_FLOATS = (262144 + 4096 + 16384 + 65536) / 4;  // kv+z+pooled+tsum
// per-token chunk bytes: xf 2048 + attn 1024 + pkv 512 = 3584
constexpr size_t PERTOK = 3584ull;

// ---------------- dtype detection ----------------
__global__ __launch_bounds__(128) void detect_kernel(
    const unsigned int* __restrict__ w, int* __restrict__ flag)
{
    __shared__ int cnt;
    if (threadIdx.x == 0) cnt = 0;
    __syncthreads();
    unsigned int v = w[threadIdx.x];
    float a = fabsf(us2f((unsigned short)(v & 0xFFFFu)));
    if (a >= 0.0625f && a <= 8.0f) atomicAdd(&cnt, 1);
    __syncthreads();
    if (threadIdx.x == 0) *flag = (cnt < 64) ? 1 : 0;
}

// ---------------- tiny init ----------------
__global__ __launch_bounds__(256) void zero_kernel(float* __restrict__ p, int n)
{
    int i = blockIdx.x * 256 + threadIdx.x;
    if (i < n) p[i] = 0.0f;
}

// ---------------- weight prep ----------------
// outT[hm][d] = sum_dh W[d][h*64+dh] * Wphi[dh][m]   (hm = h*64+m), row-major [nh*64][512]
__global__ __launch_bounds__(256) void fuse_phi_kernel(
    const void* __restrict__ W, const void* __restrict__ Wphi,
    __hip_bfloat16* __restrict__ outT, int wld, const int* __restrict__ flag)
{
    const int f = *flag;
    int o = blockIdx.x * 256 + threadIdx.x;   // o = hm*512 + d
    int hm = o >> 9, d = o & 511;
    int h = hm >> 6, m = hm & 63;
    float acc = 0.f;
    if (f) {
        const float* Wf = (const float*)W;
        const float* Pf = (const float*)Wphi;
        #pragma unroll 8
        for (int dh = 0; dh < 64; ++dh)
            acc += Wf[(size_t)d * wld + h * 64 + dh] * Pf[dh * 64 + m];
    } else {
        const __hip_bfloat16* Wb = (const __hip_bfloat16*)W;
        const __hip_bfloat16* Pb = (const __hip_bfloat16*)Wphi;
        #pragma unroll 8
        for (int dh = 0; dh < 64; ++dh)
            acc += bf2f(Wb[(size_t)d * wld + h * 64 + dh]) * bf2f(Pb[dh * 64 + m]);
    }
    outT[o] = f2bf(acc);
}

// dst[Ccols][R] = src[R][Ccols]^T, LDS-tiled 32x32
__global__ __launch_bounds__(256) void transpose_kernel(
    const void* __restrict__ src, __hip_bfloat16* __restrict__ dst, int R, int Ccols,
    const int* __restrict__ flag)
{
    __shared__ float tile[32][33];
    const int f = *flag;
    const int tx = threadIdx.x & 31, ty = threadIdx.x >> 5;   // 32 x 8
    const int c0 = blockIdx.x * 32, r0 = blockIdx.y * 32;
    #pragma unroll
    for (int k = 0; k < 4; ++k) {
        const int rl = ty + k * 8;
        tile[rl][tx] = loadElem(src, (size_t)(r0 + rl) * Ccols + c0 + tx, f);
    }
    __syncthreads();
    #pragma unroll
    for (int k = 0; k < 4; ++k) {
        const int cl = ty + k * 8;
        dst[(size_t)(c0 + cl) * R + r0 + tx] = f2bf(tile[tx][cl]);
    }
}

// ---------------- embedding gather + rmsnorm -> h (wave per row) ----------------
__global__ __launch_bounds__(256) void embed_rms_kernel(
    const int* __restrict__ ids, const void* __restrict__ emb,
    const void* __restrict__ g1, __hip_bfloat16* __restrict__ h,
    const int* __restrict__ flag)
{
    const int f = *flag;
    const int n = blockIdx.x * 4 + (threadIdx.x >> 6);   // local row in chunk
    const int lane = threadIdx.x & 63;
    const int id = ids[n];
    float x[8];
    load8(emb, (size_t)id * 512 + lane * 8, f, x);
    float ss = 0.f;
    #pragma unroll
    for (int i = 0; i < 8; ++i) ss += x[i] * x[i];
    #pragma unroll
    for (int off = 32; off; off >>= 1) ss += __shfl_xor(ss, off, 64);
    const float scale = rsqrtf(ss * (1.0f / 512.0f) + 1e-6f);
    float gv[8];
    load8(g1, (size_t)lane * 8, f, gv);
    ushort4 h0, h1;
    h0.x = f2us(x[0] * scale * gv[0]); h0.y = f2us(x[1] * scale * gv[1]);
    h0.z = f2us(x[2] * scale * gv[2]); h0.w = f2us(x[3] * scale * gv[3]);
    h1.x = f2us(x[4] * scale * gv[4]); h1.y = f2us(x[5] * scale * gv[5]);
    h1.z = f2us(x[6] * scale * gv[6]); h1.w = f2us(x[7] * scale * gv[7]);
    ushort4* ho = (ushort4*)(h + (size_t)n * 512 + lane * 8);
    ho[0] = h0; ho[1] = h1;
}

// ---------------- rmsnorm from f32 residual (chunk-local) ----------------
__global__ __launch_bounds__(256) void rms2_kernel(
    const float* __restrict__ xf, const void* __restrict__ g2,
    __hip_bfloat16* __restrict__ h, const int* __restrict__ flag)
{
    const int f = *flag;
    const int n = blockIdx.x * 4 + (threadIdx.x >> 6);
    const int lane = threadIdx.x & 63;
    const float4* xr = (const float4*)(xf + (size_t)n * 512);
    float4 a = xr[lane * 2], b = xr[lane * 2 + 1];
    float x[8] = { a.x, a.y, a.z, a.w, b.x, b.y, b.z, b.w };
    float ss = 0.f;
    #pragma unroll
    for (int i = 0; i < 8; ++i) ss += x[i] * x[i];
    #pragma unroll
    for (int off = 32; off; off >>= 1) ss += __shfl_xor(ss, off, 64);
    const float scale = rsqrtf(ss * (1.0f / 512.0f) + 1e-6f);
    float gv[8];
    load8(g2, (size_t)lane * 8, f, gv);
    ushort4 h0, h1;
    h0.x = f2us(x[0] * scale * gv[0]); h0.y = f2us(x[1] * scale * gv[1]);
    h0.z = f2us(x[2] * scale * gv[2]); h0.w = f2us(x[3] * scale * gv[3]);
    h1.x = f2us(x[4] * scale * gv[4]); h1.y = f2us(x[5] * scale * gv[5]);
    h1.z = f2us(x[6] * scale * gv[6]); h1.w = f2us(x[7] * scale * gv[7]);
    ushort4* ho = (ushort4*)(h + (size_t)n * 512 + lane * 8);
    ho[0] = h0; ho[1] = h1;
}

// ---------------- MFMA GEMM: C[M,N] = A[M,K] @ Bt[N,K]^T ----------------
// m97 structure: 128x128 tile, BK=32, global_load_lds width-16 staging, XOR swizzle.
// MODE 7: xf[row][col] = emb[ids[row]][col] + acc  (residual built in-epilogue),
//         plus column sums of the result -> pooled[b][col]  (Wo GEMM)
// MODE 8: pk|v epilogue: bn==0 -> pkv cols 0..127 = exp(-|acc|); bn==1 -> cols 128..255 = acc
template<int MODE>
__global__ __launch_bounds__(256) void gemm128_kernel(
    const __hip_bfloat16* __restrict__ A, const __hip_bfloat16* __restrict__ Bt,
    float* __restrict__ xf, __hip_bfloat16* __restrict__ Cout2,
    float* __restrict__ pooled, const int* __restrict__ ids,
    const void* __restrict__ emb, const int* __restrict__ flag, int gbase, int K)
{
    __shared__ __align__(16) char As[8192];   // bf16 [128 rows][32 k], swizzled chunks
    __shared__ __align__(16) char Bs[8192];
    __shared__ int idsL[128];

    const int tid = threadIdx.x;
    const int bm = blockIdx.x, bn = blockIdx.y;
    const int wave = tid >> 6, lane = tid & 63;
    const int quad = lane >> 4, lr = lane & 15;
    const int wm = (wave >> 1) << 6, wn = (wave & 1) << 6;

    if (MODE == 7 && tid < 128) idsL[tid] = ids[bm * 128 + tid];

    const int srow = (wave << 5) + (lane >> 2);
    const int scol = lane & 3;
    const int sfr  = (srow + (srow >> 2)) & 3;
    const int sofs = ((scol ^ sfr) << 3);

    const __hip_bfloat16* ga0 = A  + (size_t)(bm * 128 + srow) * K + sofs;
    const __hip_bfloat16* gb0 = Bt + (size_t)(bn * 128 + srow) * K + sofs;
    const __hip_bfloat16* ga1 = ga0 + (size_t)16 * K;
    const __hip_bfloat16* gb1 = gb0 + (size_t)16 * K;
    char* lA0 = As + (wave << 11);
    char* lA1 = lA0 + 1024;
    char* lB0 = Bs + (wave << 11);
    char* lB1 = lB0 + 1024;

    const int fl  = (lr + (lr >> 2)) & 3;
    const int ac  = (quad ^ fl) << 4;
    const char* arp = As + ((wm + lr) << 6) + ac;
    const char* brp = Bs + ((wn + lr) << 6) + ac;

    f32x4 acc[4][4];
    #pragma unroll
    for (int i = 0; i < 4; ++i)
        #pragma unroll
        for (int j = 0; j < 4; ++j)
            #pragma unroll
            for (int r = 0; r < 4; ++r) acc[i][j][r] = 0.0f;

    for (int k0 = 0; k0 < K; k0 += 32) {
        __syncthreads();
        gload_lds16(ga0 + k0, lA0);
        gload_lds16(ga1 + k0, lA1);
        gload_lds16(gb0 + k0, lB0);
        gload_lds16(gb1 + k0, lB1);
        __syncthreads();

        bf16x8 af[4], bfr[4];
        #pragma unroll
        for (int i = 0; i < 4; ++i)
            af[i] = *(const bf16x8*)(arp + i * 1024);
        #pragma unroll
        for (int j = 0; j < 4; ++j)
            bfr[j] = *(const bf16x8*)(brp + j * 1024);
        #pragma unroll
        for (int i = 0; i < 4; ++i)
            #pragma unroll
            for (int j = 0; j < 4; ++j)
                acc[i][j] = __builtin_amdgcn_mfma_f32_16x16x32_bf16(af[i], bfr[j], acc[i][j], 0, 0, 0);
    }

    // C/D layout: col = lane&15, row = quad*4 + reg  [m89/m91]
    const int col0 = bn * 128 + wn + lr;

    if (MODE == 7) {
        const int f = *flag;
        const int b = (gbase + bm * 128) >> 13;   // 128 | 8192 -> uniform per block
        #pragma unroll
        for (int j = 0; j < 4; ++j) {
            const int col = col0 + j * 16;
            float s = 0.f;
            #pragma unroll
            for (int i = 0; i < 4; ++i)
                #pragma unroll
                for (int r = 0; r < 4; ++r) {
                    const int rl = wm + i * 16 + quad * 4 + r;   // local row 0..127
                    const float e = loadElem(emb, (size_t)idsL[rl] * 512 + col, f);
                    const float w = e + acc[i][j][r];
                    xf[(size_t)(bm * 128 + rl) * 512 + col] = w;
                    s += w;
                }
            s += __shfl_xor(s, 16, 64);
            s += __shfl_xor(s, 32, 64);
            if (quad == 0) atomicAdd(&pooled[b * 512 + col], s);
        }
        return;
    }

    // MODE 8: pk|v
    const int row0 = bm * 128 + wm + quad * 4;
    #pragma unroll
    for (int i = 0; i < 4; ++i)
        #pragma unroll
        for (int j = 0; j < 4; ++j) {
            const int col = col0 + j * 16;   // 0..255
            #pragma unroll
            for (int r = 0; r < 4; ++r) {
                const int row = row0 + i * 16 + r;
                const float v = acc[i][j][r];
                Cout2[(size_t)row * 256 + col] = f2bf(bn == 0 ? expf(-fabsf(v)) : v);
            }
        }
}

// ---------------- fused pq-GEMM + attention mix ----------------
// Block (bm, bn): rows bm*128..+127, heads {2bn, 2bn+1} (kh = bn>>1).
// Stage 1: P = exp(-|h @ WQPt^T|) tile 128x128 (m97 K-loop) -> LDS (bf16).
// Stage 2: attn = (P @ kvT) / (P @ z + eps)  (m120 layout round-trip).
__global__ __launch_bounds__(256, 2) void pq_mix_kernel(
    const __hip_bfloat16* __restrict__ h, const __hip_bfloat16* __restrict__ WQPt,
    const float* __restrict__ kvf, const float* __restrict__ zf,
    __hip_bfloat16* __restrict__ attn, int gbase, int K)
{
    __shared__ __align__(16) char As[8192];
    __shared__ __align__(16) char Bs[8192];
    __shared__ __align__(16) char Pl[128 * 272];          // bf16 [128][136] (8-col pad)
    __shared__ __align__(16) __hip_bfloat16 kvT[80][72];

    const int tid = threadIdx.x;
    const int bm = blockIdx.x, bn = blockIdx.y;
    const int kh = bn >> 1;
    const int wave = tid >> 6, lane = tid & 63;
    const int quad = lane >> 4, lr = lane & 15;
    const int wm = (wave >> 1) << 6, wn = (wave & 1) << 6;
    const int b = (gbase + bm * 128) >> 13;               // uniform per block

    // stage kv^T + z (rows 65..79 zero) — ordered by the K-loop's first barrier
    {
        const float* kvsrc = kvf + ((size_t)b * 2 + kh) * 4096;
        for (int i = tid; i < 4096; i += 256) {
            const int m = i >> 6, dh = i & 63;
            kvT[dh][m] = f2bf(kvsrc[i]);
        }
        if (tid < 64) kvT[64][tid] = f2bf(zf[((size_t)b * 2 + kh) * 64 + tid]);
        for (int i = tid; i < 15 * 64; i += 256)
            kvT[65 + (i >> 6)][i & 63] = f2bf(0.0f);
    }

    // ---- stage 1: pq tile ----
    const int srow = (wave << 5) + (lane >> 2);
    const int scol = lane & 3;
    const int sfr  = (srow + (srow >> 2)) & 3;
    const int sofs = ((scol ^ sfr) << 3);

    const __hip_bfloat16* ga0 = h    + (size_t)(bm * 128 + srow) * K + sofs;
    const __hip_bfloat16* gb0 = WQPt + (size_t)(bn * 128 + srow) * K + sofs;
    const __hip_bfloat16* ga1 = ga0 + (size_t)16 * K;
    const __hip_bfloat16* gb1 = gb0 + (size_t)16 * K;
    char* lA0 = As + (wave << 11);
    char* lA1 = lA0 + 1024;
    char* lB0 = Bs + (wave << 11);
    char* lB1 = lB0 + 1024;

    const int fl  = (lr + (lr >> 2)) & 3;
    const int ac  = (quad ^ fl) << 4;
    const char* arp = As + ((wm + lr) << 6) + ac;
    const char* brp = Bs + ((wn + lr) << 6) + ac;

    f32x4 acc[4][4];
    #pragma unroll
    for (int i = 0; i < 4; ++i)
        #pragma unroll
        for (int j = 0; j < 4; ++j)
            #pragma unroll
            for (int r = 0; r < 4; ++r) acc[i][j][r] = 0.0f;

    for (int k0 = 0; k0 < K; k0 += 32) {
        __syncthreads();
        gload_lds16(ga0 + k0, lA0);
        gload_lds16(ga1 + k0, lA1);
        gload_lds16(gb0 + k0, lB0);
        gload_lds16(gb1 + k0, lB1);
        __syncthreads();

        bf16x8 af[4], bfr[4];
        #pragma unroll
        for (int i = 0; i < 4; ++i)
            af[i] = *(const bf16x8*)(arp + i * 1024);
        #pragma unroll
        for (int j = 0; j < 4; ++j)
            bfr[j] = *(const bf16x8*)(brp + j * 1024);
        #pragma unroll
        for (int i = 0; i < 4; ++i)
            #pragma unroll
            for (int j = 0; j < 4; ++j)
                acc[i][j] = __builtin_amdgcn_mfma_f32_16x16x32_bf16(af[i], bfr[j], acc[i][j], 0, 0, 0);
    }

    // P = exp(-|acc|) -> LDS (C-layout write: row = wm+i*16+quad*4+r, col = wn+j*16+lr)
    #pragma unroll
    for (int i = 0; i < 4; ++i)
        #pragma unroll
        for (int j = 0; j < 4; ++j)
            #pragma unroll
            for (int r = 0; r < 4; ++r) {
                const int rl = wm + i * 16 + quad * 4 + r;
                const int cl = wn + j * 16 + lr;
                *(__hip_bfloat16*)(Pl + rl * 272 + cl * 2) = f2bf(expf(-fabsf(acc[i][j][r])));
            }
    __syncthreads();

    // ---- stage 2: attn = (P @ kvT) / (P @ z + eps) ----
    // wave w: rows wm (same), head-local hl = wave&1 (P cols wn..wn+63).
    const int hl = wave & 1;
    f32x4 acc2[4][5];
    #pragma unroll
    for (int i = 0; i < 4; ++i)
        #pragma unroll
        for (int j = 0; j < 5; ++j)
            #pragma unroll
            for (int r = 0; r < 4; ++r) acc2[i][j][r] = 0.0f;

    #pragma unroll
    for (int kk = 0; kk < 2; ++kk) {
        const int kofs = kk * 32 + quad * 8;              // m-offset within head
        bf16x8 af[4], bfr[5];
        #pragma unroll
        for (int i = 0; i < 4; ++i)
            af[i] = *(const bf16x8*)(Pl + (wm + i * 16 + lr) * 272 + (wn + kofs) * 2);
        #pragma unroll
        for (int j = 0; j < 5; ++j)
            bfr[j] = *(const bf16x8*)&kvT[j * 16 + lr][kofs];
        #pragma unroll
        for (int i = 0; i < 4; ++i)
            #pragma unroll
            for (int j = 0; j < 5; ++j)
                acc2[i][j] = __builtin_amdgcn_mfma_f32_16x16x32_bf16(af[i], bfr[j], acc2[i][j], 0, 0, 0);
    }

    const int colb = (bn * 2 + hl) * 64;                  // global head col base
    #pragma unroll
    for (int i = 0; i < 4; ++i) {
        const int rowb = bm * 128 + wm + i * 16 + quad * 4;
        #pragma unroll
        for (int r = 0; r < 4; ++r) {
            const float den = __shfl(acc2[i][4][r], lane & 48, 64);
            const float inv = 1.0f / (den + 1e-6f);
            const size_t base = (size_t)(rowb + r) * 512 + colb;
            #pragma unroll
            for (int j = 0; j < 4; ++j)
                attn[base + j * 16 + lr] = f2bf(acc2[i][j][r] * inv);
        }
    }
}

// ---------------- fused SwiGLU up-GEMM + column-sum (barrier-free, 2 blocks/CU) ----------------
// Block = 64 A-rows, FULL K=512 staged once in LDS (64 KiB, XOR-swizzled), then NO
// barriers in the main loop. 8 waves each own 256 ffn cols (8 chunks x 32), reading
// A-fragments from LDS and Wg/Wu fragments straight from global (L2-resident).
// 64 KiB + 8 KiB LDS -> 2 blocks/CU -> 4 waves/SIMD: TLP hides per-wave load latency
// (round-4 lesson: explicit reg-pipelining spills at this acc footprint; occupancy is
// the non-spilling way to overlap LDS/VMEM/MFMA pipes).
// acc = 4m x 2c x 2 = 64 VGPR; total ~110 < 128 -> fits __launch_bounds__(512, 4).
__global__ __launch_bounds__(512, 4) void ffn8_kernel(
    const __hip_bfloat16* __restrict__ A, const __hip_bfloat16* __restrict__ Bg,
    const __hip_bfloat16* __restrict__ Bu, float* __restrict__ tsum, int gbase)
{
    __shared__ __align__(16) char L[65536];    // A [64 rows][64 slots of 16B], slot^=(row&7)
    __shared__ float sBuf[2048];               // [wave][ci][c][lr] col-sums

    const int tid = threadIdx.x;
    const int bm = blockIdx.x;
    const int wave = tid >> 6, lane = tid & 63;
    const int quad = lane >> 4, lr = lane & 15;

    // ---- stage A-tile once: wave w stages rows w, w+8, ..., w+56 ----
    // LDS linear (dest = base + lane*16); SOURCE slot carries the inverse swizzle
    // (row&7 == wave for every staged row since stride 8).
    {
        const int ss = (lane & 56) | ((lane ^ wave) & 7);
        const __hip_bfloat16* gsrc = A + (size_t)(bm * 64 + wave) * 512 + ss * 8;
        char* ldst = L + wave * 1024;
        #pragma unroll
        for (int i = 0; i < 8; ++i)
            gload_lds16(gsrc + (size_t)i * 8 * 512, ldst + i * 8192);
    }
    asm volatile("s_waitcnt vmcnt(0)" ::: "memory");
    __syncthreads();

    // A-frag (m, ks): row m*16+lr (m<4), byte = row*1024 + (((ks*4+quad) ^ (lr&7)) << 4)
    const int x7s = (lr & 7) << 4;
    const char* apq = L + (lr << 10);

    // B: wave owns cols wave*256..+255; fragment row = colbase + ci*32 + cf*16 + lr
    const __hip_bfloat16* pG = Bg + (size_t)(wave * 256 + lr) * 512 + quad * 8;
    const __hip_bfloat16* pU = Bu + (size_t)(wave * 256 + lr) * 512 + quad * 8;

    const int b = (gbase + bm * 64) >> 13;    // 64 | 8192 -> uniform per block

    for (int ci = 0; ci < 8; ++ci) {
        const __hip_bfloat16* pGc = pG + (size_t)ci * 32 * 512;
        const __hip_bfloat16* pUc = pU + (size_t)ci * 32 * 512;

        f32x4 aG[4][2], aU[4][2];
        #pragma unroll
        for (int m = 0; m < 4; ++m)
            #pragma unroll
            for (int c = 0; c < 2; ++c)
                #pragma unroll
                for (int r = 0; r < 4; ++r) { aG[m][c][r] = 0.0f; aU[m][c][r] = 0.0f; }

        #pragma unroll 4
        for (int ks = 0; ks < 16; ++ks) {
            const int so = ((ks << 6) | (quad << 4)) ^ x7s;
            bf16x8 af[4];
            #pragma unroll
            for (int m = 0; m < 4; ++m)
                af[m] = *(const bf16x8*)(apq + m * 16384 + so);
            bf16x8 bg0 = *(const bf16x8*)(pGc + ks * 32);
            bf16x8 bg1 = *(const bf16x8*)(pGc + 16 * 512 + ks * 32);
            bf16x8 bu0 = *(const bf16x8*)(pUc + ks * 32);
            bf16x8 bu1 = *(const bf16x8*)(pUc + 16 * 512 + ks * 32);
            #pragma unroll
            for (int m = 0; m < 4; ++m) {
                aG[m][0] = __builtin_amdgcn_mfma_f32_16x16x32_bf16(af[m], bg0, aG[m][0], 0, 0, 0);
                aG[m][1] = __builtin_amdgcn_mfma_f32_16x16x32_bf16(af[m], bg1, aG[m][1], 0, 0, 0);
                aU[m][0] = __builtin_amdgcn_mfma_f32_16x16x32_bf16(af[m], bu0, aU[m][0], 0, 0, 0);
                aU[m][1] = __builtin_amdgcn_mfma_f32_16x16x32_bf16(af[m], bu1, aU[m][1], 0, 0, 0);
            }
        }

        // ---- chunk epilogue: colsum of silu(g)*u over this block's 64 rows ----
        #pragma unroll
        for (int c = 0; c < 2; ++c) {
            float s = 0.f;
            #pragma unroll
            for (int m = 0; m < 4; ++m)
                #pragma unroll
                for (int r = 0; r < 4; ++r) {
                    const float g = aG[m][c][r];
                    s += (g / (1.0f + expf(-g))) * aU[m][c][r];
                }
            s += __shfl_xor(s, 16, 64);
            s += __shfl_xor(s, 32, 64);
            if (quad == 0) sBuf[wave * 256 + ci * 32 + c * 16 + lr] = s;
        }
    }

    // ---- drain: one atomic pass (sBuf index == tsum col) ----
    __syncthreads();
    #pragma unroll
    for (int i = 0; i < 4; ++i) {
        const int idx = tid * 4 + i;
        atomicAdd(&tsum[b * 2048 + idx], sBuf[idx]);
    }
}

// ---------------- pooled[b][:] += tsum[b][:] @ Wd  (k-split parallel) ----------------
__global__ __launch_bounds__(256) void ffn_pool_kernel(
    const float* __restrict__ tsum, const void* __restrict__ Wd,
    float* __restrict__ pooled, const int* __restrict__ flag)
{
    __shared__ float ts[8][64];
    const int f = *flag;
    const int k0 = blockIdx.x * 64;
    const int t = threadIdx.x;
    for (int i = t; i < 512; i += 256)
        ts[i >> 6][i & 63] = tsum[(i >> 6) * 2048 + k0 + (i & 63)];
    __syncthreads();

    float acc0[8] = {}, acc1[8] = {};
    for (int kk = 0; kk < 64; ++kk) {
        const size_t krow = (size_t)(k0 + kk) * 512;
        const float w0 = loadElem(Wd, krow + t, f);
        const float w1 = loadElem(Wd, krow + t + 256, f);
        #pragma unroll
        for (int b = 0; b < 8; ++b) {
            acc0[b] += ts[b][kk] * w0;
            acc1[b] += ts[b][kk] * w1;
        }
    }
    #pragma unroll
    for (int b = 0; b < 8; ++b) {
        atomicAdd(&pooled[b * 512 + t], acc0[b]);
        atomicAdd(&pooled[b * 512 + t + 256], acc1[b]);
    }
}

// ---------------- kv / z global-state reduction (pkv [C][256] input) ----------------
__global__ __launch_bounds__(256) void kv_z_kernel(
    const __hip_bfloat16* __restrict__ pkv,
    float* __restrict__ kv, float* __restrict__ z, int gbase, int nrows)
{
    __shared__ float pks[8][64], vs[8][64];
    const int slab = blockIdx.x, kh = blockIdx.y;
    const int b = (gbase + slab * nrows) >> 13;
    const int tid = threadIdx.x;
    const int tm = (tid & 15) << 2, tdh = (tid >> 4) << 2;
    const int lss = tid >> 5, lmm = (tid & 31) << 1;

    float acc[4][4] = {};
    float zacc[4] = {};
    for (int sb = 0; sb < nrows; sb += 8) {
        __syncthreads();
        {
            const size_t n = (size_t)slab * nrows + sb + lss;
            const __hip_bfloat16* pr = pkv + n * 256 + kh * 64 + lmm;
            const __hip_bfloat16* vr = pkv + n * 256 + 128 + kh * 64 + lmm;
            pks[lss][lmm]     = bf2f(pr[0]);
            pks[lss][lmm + 1] = bf2f(pr[1]);
            vs[lss][lmm]      = bf2f(vr[0]);
            vs[lss][lmm + 1]  = bf2f(vr[1]);
        }
        __syncthreads();
        #pragma unroll
        for (int ss = 0; ss < 8; ++ss) {
            f32x4 p = *(const f32x4*)&pks[ss][tm];
            f32x4 w = *(const f32x4*)&vs[ss][tdh];
            #pragma unroll
            for (int i = 0; i < 4; ++i)
                #pragma unroll
                for (int j = 0; j < 4; ++j)
                    acc[i][j] += p[i] * w[j];
            if ((tid >> 4) == 0) {
                #pragma unroll
                for (int i = 0; i < 4; ++i) zacc[i] += p[i];
            }
        }
    }
    #pragma unroll
    for (int i = 0; i < 4; ++i)
        #pragma unroll
        for (int j = 0; j < 4; ++j)
            atomicAdd(&kv[(((size_t)b * 2 + kh) * 64 + tm + i) * 64 + tdh + j], acc[i][j]);
    if ((tid >> 4) == 0) {
        #pragma unroll
        for (int i = 0; i < 4; ++i)
            atomicAdd(&z[((size_t)b * 2 + kh) * 64 + tm + i], zacc[i]);
    }
}

// ---------------- classifier head ----------------
__global__ __launch_bounds__(256) void head_kernel(
    const float* __restrict__ pooled, const void* __restrict__ Wc,
    const void* __restrict__ bc, void* __restrict__ out, const int* __restrict__ flag)
{
    const int f = *flag;
    const int t = threadIdx.x;
    const int grp = t >> 4, ln = t & 15;
    const int b = grp >> 1, c = grp & 1;
    float p = 0.f;
    for (int d = ln; d < 512; d += 16)
        p += pooled[b * 512 + d] * loadElem(Wc, (size_t)d * 2 + c, f);
    #pragma unroll
    for (int off = 8; off; off >>= 1) p += __shfl_xor(p, off, 64);
    if (ln == 0) {
        const float val = p * (1.0f / 8192.0f) + loadElem(bc, c, f);
        if (f) ((float*)out)[b * 2 + c] = val;
        else   ((__hip_bfloat16*)out)[b * 2 + c] = f2bf(val);
    }
}

// ---------------- launch ----------------
extern "C" void kernel_launch(void* const* d_in, const int* in_sizes, int n_in,
                              void* d_out, int out_size, void* d_ws, size_t ws_size,
                              hipStream_t stream)
{
    const int* ids   = (const int*)d_in[0];
    const void* emb  = d_in[1];
    const void* Wq   = d_in[2];
    const void* Wk   = d_in[3];
    const void* Wv   = d_in[4];
    const void* Wph  = d_in[5];
    const void* Wo   = d_in[6];
    const void* g1   = d_in[7];
    const void* g2   = d_in[8];
    const void* Wg   = d_in[9];
    const void* Wu   = d_in[10];
    const void* Wd   = d_in[11];
    const void* Wc   = d_in[12];
    const void* bc   = d_in[13];

    char* ws = (char*)d_ws;
    __hip_bfloat16* WQPt  = (__hip_bfloat16*)(ws + OFF_WQPT);
    __hip_bfloat16* WKPt  = (__hip_bfloat16*)(ws + OFF_WKPT);  // [WKPt|WvT] = [256][512]
    __hip_bfloat16* WvT   = (__hip_bfloat16*)(ws + OFF_WVT);
    __hip_bfloat16* WoT   = (__hip_bfloat16*)(ws + OFF_WOT);
    __hip_bfloat16* WgT   = (__hip_bfloat16*)(ws + OFF_WGT);
    __hip_bfloat16* WuT   = (__hip_bfloat16*)(ws + OFF_WUT);
    float*          kv    = (float*)(ws + OFF_KV);
    float*          z     = (float*)(ws + OFF_Z);
    float*          pooled= (float*)(ws + OFF_POOL);
    float*          tsum  = (float*)(ws + OFF_TSUM);
    int*            flag  = (int*)(ws + OFF_FLAG);
    __hip_bfloat16* hall  = (__hip_bfloat16*)(ws + OFF_H);     // bf16 [65536][512], persistent

    // ---- adaptive chunk: largest power-of-2 C in [256, 32768] that fits ws ----
    int C = 32768;
    while (C > 256 && CHUNKBASE + PERTOK * (size_t)C > ws_size) C >>= 1;
    const int NC = NTOK / C;

    char* cb = ws + CHUNKBASE;
    float*          xf   = (float*)cb;                                  // f32  [C][512]
    __hip_bfloat16* attn = (__hip_bfloat16*)(cb + (size_t)C * 2048);    // bf16 [C][512]
    __hip_bfloat16* pkv  = (__hip_bfloat16*)(cb + (size_t)C * 3072);    // bf16 [C][256]

    detect_kernel<<<1, 128, 0, stream>>>((const unsigned int*)Wph, flag);
    zero_kernel<<<(ZERO_FLOATS + 255) / 256, 256, 0, stream>>>(kv, ZERO_FLOATS);

    // weight prep
    fuse_phi_kernel<<<1024, 256, 0, stream>>>(Wq, Wph, WQPt, 512, flag);
    fuse_phi_kernel<<<256, 256, 0, stream>>>(Wk, Wph, WKPt, 128, flag);
    transpose_kernel<<<dim3(128 / 32, 512 / 32), 256, 0, stream>>>(Wv, WvT, 512, 128, flag);
    transpose_kernel<<<dim3(512 / 32, 512 / 32), 256, 0, stream>>>(Wo, WoT, 512, 512, flag);
    transpose_kernel<<<dim3(2048 / 32, 512 / 32), 256, 0, stream>>>(Wg, WgT, 512, 2048, flag);
    transpose_kernel<<<dim3(2048 / 32, 512 / 32), 256, 0, stream>>>(Wu, WuT, 512, 2048, flag);

    // ---- pass A: per chunk h -> pk|v -> accumulate global kv / z ----
    // h is written to its persistent slot so pass B reuses it (no re-gather/re-norm).
    for (int c = 0; c < NC; ++c) {
        const int g0 = c * C;
        __hip_bfloat16* hc = hall + (size_t)g0 * 512;
        embed_rms_kernel<<<C / 4, 256, 0, stream>>>(ids + g0, emb, g1, hc, flag);
        gemm128_kernel<8><<<dim3(C / 128, 2), 256, 0, stream>>>(
            hc, WKPt, nullptr, pkv, nullptr, nullptr, nullptr, flag, g0, 512);
        kv_z_kernel<<<dim3(C / 128, 2), 256, 0, stream>>>(pkv, kv, z, g0, 128);
    }

    // ---- pass B: per chunk (stored h) -> fused pq+mix -> Wo(+emb residual,+pool) -> rms -> ffn ----
    for (int c = 0; c < NC; ++c) {
        const int g0 = c * C;
        __hip_bfloat16* hc = hall + (size_t)g0 * 512;
        pq_mix_kernel<<<dim3(C / 128, 4), 256, 0, stream>>>(
            hc, WQPt, kv, z, attn, g0, 512);
        gemm128_kernel<7><<<dim3(C / 128, 4), 256, 0, stream>>>(
            attn, WoT, xf, nullptr, pooled, ids + g0, emb, flag, g0, 512);
        rms2_kernel<<<C / 4, 256, 0, stream>>>(xf, g2, hc, flag);   // overwrites hc with h2
        ffn8_kernel<<<C / 64, 512, 0, stream>>>(hc, WgT, WuT, tsum, g0);
    }

    // pooled += tsum @ Wd  (exact: pooling is linear; k-split parallel)
    ffn_pool_kernel<<<32, 256, 0, stream>>>(tsum, Wd, pooled, flag);

    head_kernel<<<1, 256, 0, stream>>>(pooled, Wc, bc, d_out, flag);
}

// Round 6
// 909.431 us; speedup vs baseline: 1.2336x; 1.2336x over previous
//
#include <hip/hip_runtime.h>
#include <hip/hip_bf16.h>
#include <math.h>

// ---------------- types / helpers ----------------
typedef __attribute__((ext_vector_type(8))) short bf16x8;
typedef __attribute__((ext_vector_type(4))) float f32x4;

#define DEV static __device__ __forceinline__
#define AS1 __attribute__((address_space(1)))
#define AS3 __attribute__((address_space(3)))

DEV float bf2f(__hip_bfloat16 v) { return __bfloat162float(v); }
DEV __hip_bfloat16 f2bf(float f) { return __float2bfloat16(f); }
DEV float us2f(unsigned short u) { return __uint_as_float(((unsigned int)u) << 16); }
DEV unsigned short f2us(float f) {
    __hip_bfloat16 b = __float2bfloat16(f);
    return *(unsigned short*)&b;
}

// async global->LDS, 16 B per lane (LDS dst = wave-uniform base + lane*16)
DEV void gload_lds16(const void* g, void* l) {
    __builtin_amdgcn_global_load_lds((const AS1 unsigned int*)g,
                                     (AS3 unsigned int*)l, 16, 0, 0);
}

// load 8 consecutive floats from an input tensor that is either f32 or bf16
DEV void load8(const void* p, size_t off, int f32m, float* o) {
    if (f32m) {
        const float4* r = (const float4*)((const float*)p + off);
        float4 A = r[0], B = r[1];
        o[0] = A.x; o[1] = A.y; o[2] = A.z; o[3] = A.w;
        o[4] = B.x; o[5] = B.y; o[6] = B.z; o[7] = B.w;
    } else {
        const ushort4* r = (const ushort4*)((const __hip_bfloat16*)p + off);
        ushort4 A = r[0], B = r[1];
        o[0] = us2f(A.x); o[1] = us2f(A.y); o[2] = us2f(A.z); o[3] = us2f(A.w);
        o[4] = us2f(B.x); o[5] = us2f(B.y); o[6] = us2f(B.z); o[7] = us2f(B.w);
    }
}

DEV float loadElem(const void* p, size_t idx, int f32m) {
    return f32m ? ((const float*)p)[idx] : bf2f(((const __hip_bfloat16*)p)[idx]);
}

// ---------------- problem constants ----------------
// B=8 S=8192 D=512 H=8 HK=2 DH=64 M=64 DFF=2048 NCLS=2 G=4
constexpr int NTOK = 65536;   // 8*8192

// ---------------- persistent ws layout (bytes) ----------------
constexpr size_t OFF_WQPT = 0;                       // bf16 [512][512]  (Wq@Wphi)^T
constexpr size_t OFF_WKPT = OFF_WQPT + 524288ull;    // bf16 [128][512]  (Wk@Wphi)^T   } contiguous:
constexpr size_t OFF_WVT  = OFF_WKPT + 131072ull;    // bf16 [128][512]  Wv^T          } [256][512]
constexpr size_t OFF_WOT  = OFF_WVT  + 131072ull;    // bf16 [512][512]  Wo^T
constexpr size_t OFF_WGT  = OFF_WOT  + 524288ull;    // bf16 [2048][512] Wg^T
constexpr size_t OFF_WUT  = OFF_WGT  + 2097152ull;   // bf16 [2048][512] Wu^T
constexpr size_t OFF_KV   = OFF_WUT  + 2097152ull;   // f32  [8][2][64][64]
constexpr size_t OFF_Z    = OFF_KV   + 262144ull;    // f32  [8][2][64]
constexpr size_t OFF_POOL = OFF_Z    + 4096ull;      // f32  [8][512]
constexpr size_t OFF_TSUM = OFF_POOL + 16384ull;     // f32  [8][2048]  col-sums of FFN t
constexpr size_t OFF_FLAG = OFF_TSUM + 65536ull;     // int  dtype flag (1 = f32 inputs)
constexpr size_t PERSIST  = OFF_FLAG + 256ull;
// h is persistent for ALL tokens (pass A writes, pass B reads then overwrites per-chunk)
constexpr size_t OFF_H    = PERSIST;                 // bf16 [65536][512] = 64 MB
constexpr size_t CHUNKBASE = OFF_H + 67108864ull;
constexpr int    ZERO_FLOATS = (262144 + 4096 + 16384 + 65536) / 4;  // kv+z+pooled+tsum
// per-token chunk bytes: xf 2048 + attn 1024 + pkv 512 = 3584
constexpr size_t PERTOK = 3584ull;
// C=65536 needs 73 MB + 235 MB = 308 MB; adaptive loop falls back to 32768 (190 MB) if ws is smaller.

// ---------------- dtype detection ----------------
__global__ __launch_bounds__(128) void detect_kernel(
    const unsigned int* __restrict__ w, int* __restrict__ flag)
{
    __shared__ int cnt;
    if (threadIdx.x == 0) cnt = 0;
    __syncthreads();
    unsigned int v = w[threadIdx.x];
    float a = fabsf(us2f((unsigned short)(v & 0xFFFFu)));
    if (a >= 0.0625f && a <= 8.0f) atomicAdd(&cnt, 1);
    __syncthreads();
    if (threadIdx.x == 0) *flag = (cnt < 64) ? 1 : 0;
}

// ---------------- tiny init ----------------
__global__ __launch_bounds__(256) void zero_kernel(float* __restrict__ p, int n)
{
    int i = blockIdx.x * 256 + threadIdx.x;
    if (i < n) p[i] = 0.0f;
}

// ---------------- weight prep ----------------
// outT[hm][d] = sum_dh W[d][h*64+dh] * Wphi[dh][m]   (hm = h*64+m), row-major [nh*64][512]
__global__ __launch_bounds__(256) void fuse_phi_kernel(
    const void* __restrict__ W, const void* __restrict__ Wphi,
    __hip_bfloat16* __restrict__ outT, int wld, const int* __restrict__ flag)
{
    const int f = *flag;
    int o = blockIdx.x * 256 + threadIdx.x;   // o = hm*512 + d
    int hm = o >> 9, d = o & 511;
    int h = hm >> 6, m = hm & 63;
    float acc = 0.f;
    if (f) {
        const float* Wf = (const float*)W;
        const float* Pf = (const float*)Wphi;
        #pragma unroll 8
        for (int dh = 0; dh < 64; ++dh)
            acc += Wf[(size_t)d * wld + h * 64 + dh] * Pf[dh * 64 + m];
    } else {
        const __hip_bfloat16* Wb = (const __hip_bfloat16*)W;
        const __hip_bfloat16* Pb = (const __hip_bfloat16*)Wphi;
        #pragma unroll 8
        for (int dh = 0; dh < 64; ++dh)
            acc += bf2f(Wb[(size_t)d * wld + h * 64 + dh]) * bf2f(Pb[dh * 64 + m]);
    }
    outT[o] = f2bf(acc);
}

// dst[Ccols][R] = src[R][Ccols]^T, LDS-tiled 32x32
__global__ __launch_bounds__(256) void transpose_kernel(
    const void* __restrict__ src, __hip_bfloat16* __restrict__ dst, int R, int Ccols,
    const int* __restrict__ flag)
{
    __shared__ float tile[32][33];
    const int f = *flag;
    const int tx = threadIdx.x & 31, ty = threadIdx.x >> 5;   // 32 x 8
    const int c0 = blockIdx.x * 32, r0 = blockIdx.y * 32;
    #pragma unroll
    for (int k = 0; k < 4; ++k) {
        const int rl = ty + k * 8;
        tile[rl][tx] = loadElem(src, (size_t)(r0 + rl) * Ccols + c0 + tx, f);
    }
    __syncthreads();
    #pragma unroll
    for (int k = 0; k < 4; ++k) {
        const int cl = ty + k * 8;
        dst[(size_t)(c0 + cl) * R + r0 + tx] = f2bf(tile[tx][cl]);
    }
}

// ---------------- embedding gather + rmsnorm -> h (wave per row) ----------------
__global__ __launch_bounds__(256) void embed_rms_kernel(
    const int* __restrict__ ids, const void* __restrict__ emb,
    const void* __restrict__ g1, __hip_bfloat16* __restrict__ h,
    const int* __restrict__ flag)
{
    const int f = *flag;
    const int n = blockIdx.x * 4 + (threadIdx.x >> 6);   // local row in chunk
    const int lane = threadIdx.x & 63;
    const int id = ids[n];
    float x[8];
    load8(emb, (size_t)id * 512 + lane * 8, f, x);
    float ss = 0.f;
    #pragma unroll
    for (int i = 0; i < 8; ++i) ss += x[i] * x[i];
    #pragma unroll
    for (int off = 32; off; off >>= 1) ss += __shfl_xor(ss, off, 64);
    const float scale = rsqrtf(ss * (1.0f / 512.0f) + 1e-6f);
    float gv[8];
    load8(g1, (size_t)lane * 8, f, gv);
    ushort4 h0, h1;
    h0.x = f2us(x[0] * scale * gv[0]); h0.y = f2us(x[1] * scale * gv[1]);
    h0.z = f2us(x[2] * scale * gv[2]); h0.w = f2us(x[3] * scale * gv[3]);
    h1.x = f2us(x[4] * scale * gv[4]); h1.y = f2us(x[5] * scale * gv[5]);
    h1.z = f2us(x[6] * scale * gv[6]); h1.w = f2us(x[7] * scale * gv[7]);
    ushort4* ho = (ushort4*)(h + (size_t)n * 512 + lane * 8);
    ho[0] = h0; ho[1] = h1;
}

// ---------------- rmsnorm from f32 residual (chunk-local) ----------------
__global__ __launch_bounds__(256) void rms2_kernel(
    const float* __restrict__ xf, const void* __restrict__ g2,
    __hip_bfloat16* __restrict__ h, const int* __restrict__ flag)
{
    const int f = *flag;
    const int n = blockIdx.x * 4 + (threadIdx.x >> 6);
    const int lane = threadIdx.x & 63;
    const float4* xr = (const float4*)(xf + (size_t)n * 512);
    float4 a = xr[lane * 2], b = xr[lane * 2 + 1];
    float x[8] = { a.x, a.y, a.z, a.w, b.x, b.y, b.z, b.w };
    float ss = 0.f;
    #pragma unroll
    for (int i = 0; i < 8; ++i) ss += x[i] * x[i];
    #pragma unroll
    for (int off = 32; off; off >>= 1) ss += __shfl_xor(ss, off, 64);
    const float scale = rsqrtf(ss * (1.0f / 512.0f) + 1e-6f);
    float gv[8];
    load8(g2, (size_t)lane * 8, f, gv);
    ushort4 h0, h1;
    h0.x = f2us(x[0] * scale * gv[0]); h0.y = f2us(x[1] * scale * gv[1]);
    h0.z = f2us(x[2] * scale * gv[2]); h0.w = f2us(x[3] * scale * gv[3]);
    h1.x = f2us(x[4] * scale * gv[4]); h1.y = f2us(x[5] * scale * gv[5]);
    h1.z = f2us(x[6] * scale * gv[6]); h1.w = f2us(x[7] * scale * gv[7]);
    ushort4* ho = (ushort4*)(h + (size_t)n * 512 + lane * 8);
    ho[0] = h0; ho[1] = h1;
}

// ---------------- MFMA GEMM: C[M,N] = A[M,K] @ Bt[N,K]^T ----------------
// m97 structure: 128x128 tile, BK=32, global_load_lds width-16 staging, XOR swizzle.
// MODE 7: xf[row][col] = emb[ids[row]][col] + acc  (residual built in-epilogue),
//         plus column sums of the result -> pooled[b][col]  (Wo GEMM)
// MODE 8: pk|v epilogue: bn==0 -> pkv cols 0..127 = exp(-|acc|); bn==1 -> cols 128..255 = acc
template<int MODE>
__global__ __launch_bounds__(256) void gemm128_kernel(
    const __hip_bfloat16* __restrict__ A, const __hip_bfloat16* __restrict__ Bt,
    float* __restrict__ xf, __hip_bfloat16* __restrict__ Cout2,
    float* __restrict__ pooled, const int* __restrict__ ids,
    const void* __restrict__ emb, const int* __restrict__ flag, int gbase, int K)
{
    __shared__ __align__(16) char As[8192];   // bf16 [128 rows][32 k], swizzled chunks
    __shared__ __align__(16) char Bs[8192];
    __shared__ int idsL[128];

    const int tid = threadIdx.x;
    const int bm = blockIdx.x, bn = blockIdx.y;
    const int wave = tid >> 6, lane = tid & 63;
    const int quad = lane >> 4, lr = lane & 15;
    const int wm = (wave >> 1) << 6, wn = (wave & 1) << 6;

    if (MODE == 7 && tid < 128) idsL[tid] = ids[bm * 128 + tid];

    const int srow = (wave << 5) + (lane >> 2);
    const int scol = lane & 3;
    const int sfr  = (srow + (srow >> 2)) & 3;
    const int sofs = ((scol ^ sfr) << 3);

    const __hip_bfloat16* ga0 = A  + (size_t)(bm * 128 + srow) * K + sofs;
    const __hip_bfloat16* gb0 = Bt + (size_t)(bn * 128 + srow) * K + sofs;
    const __hip_bfloat16* ga1 = ga0 + (size_t)16 * K;
    const __hip_bfloat16* gb1 = gb0 + (size_t)16 * K;
    char* lA0 = As + (wave << 11);
    char* lA1 = lA0 + 1024;
    char* lB0 = Bs + (wave << 11);
    char* lB1 = lB0 + 1024;

    const int fl  = (lr + (lr >> 2)) & 3;
    const int ac  = (quad ^ fl) << 4;
    const char* arp = As + ((wm + lr) << 6) + ac;
    const char* brp = Bs + ((wn + lr) << 6) + ac;

    f32x4 acc[4][4];
    #pragma unroll
    for (int i = 0; i < 4; ++i)
        #pragma unroll
        for (int j = 0; j < 4; ++j)
            #pragma unroll
            for (int r = 0; r < 4; ++r) acc[i][j][r] = 0.0f;

    for (int k0 = 0; k0 < K; k0 += 32) {
        __syncthreads();
        gload_lds16(ga0 + k0, lA0);
        gload_lds16(ga1 + k0, lA1);
        gload_lds16(gb0 + k0, lB0);
        gload_lds16(gb1 + k0, lB1);
        __syncthreads();

        bf16x8 af[4], bfr[4];
        #pragma unroll
        for (int i = 0; i < 4; ++i)
            af[i] = *(const bf16x8*)(arp + i * 1024);
        #pragma unroll
        for (int j = 0; j < 4; ++j)
            bfr[j] = *(const bf16x8*)(brp + j * 1024);
        #pragma unroll
        for (int i = 0; i < 4; ++i)
            #pragma unroll
            for (int j = 0; j < 4; ++j)
                acc[i][j] = __builtin_amdgcn_mfma_f32_16x16x32_bf16(af[i], bfr[j], acc[i][j], 0, 0, 0);
    }

    // C/D layout: col = lane&15, row = quad*4 + reg  [m89/m91]
    const int col0 = bn * 128 + wn + lr;

    if (MODE == 7) {
        const int f = *flag;
        const int b = (gbase + bm * 128) >> 13;   // 128 | 8192 -> uniform per block
        #pragma unroll
        for (int j = 0; j < 4; ++j) {
            const int col = col0 + j * 16;
            float s = 0.f;
            #pragma unroll
            for (int i = 0; i < 4; ++i)
                #pragma unroll
                for (int r = 0; r < 4; ++r) {
                    const int rl = wm + i * 16 + quad * 4 + r;   // local row 0..127
                    const float e = loadElem(emb, (size_t)idsL[rl] * 512 + col, f);
                    const float w = e + acc[i][j][r];
                    xf[(size_t)(bm * 128 + rl) * 512 + col] = w;
                    s += w;
                }
            s += __shfl_xor(s, 16, 64);
            s += __shfl_xor(s, 32, 64);
            if (quad == 0) atomicAdd(&pooled[b * 512 + col], s);
        }
        return;
    }

    // MODE 8: pk|v
    const int row0 = bm * 128 + wm + quad * 4;
    #pragma unroll
    for (int i = 0; i < 4; ++i)
        #pragma unroll
        for (int j = 0; j < 4; ++j) {
            const int col = col0 + j * 16;   // 0..255
            #pragma unroll
            for (int r = 0; r < 4; ++r) {
                const int row = row0 + i * 16 + r;
                const float v = acc[i][j][r];
                Cout2[(size_t)row * 256 + col] = f2bf(bn == 0 ? expf(-fabsf(v)) : v);
            }
        }
}

// ---------------- fused pq-GEMM + attention mix ----------------
// Block (bm, bn): rows bm*128..+127, heads {2bn, 2bn+1} (kh = bn>>1).
// Stage 1: P = exp(-|h @ WQPt^T|) tile 128x128 (m97 K-loop) -> LDS (bf16).
// Stage 2: attn = (P @ kvT) / (P @ z + eps)  (m120 layout round-trip).
__global__ __launch_bounds__(256, 2) void pq_mix_kernel(
    const __hip_bfloat16* __restrict__ h, const __hip_bfloat16* __restrict__ WQPt,
    const float* __restrict__ kvf, const float* __restrict__ zf,
    __hip_bfloat16* __restrict__ attn, int gbase, int K)
{
    __shared__ __align__(16) char As[8192];
    __shared__ __align__(16) char Bs[8192];
    __shared__ __align__(16) char Pl[128 * 272];          // bf16 [128][136] (8-col pad)
    __shared__ __align__(16) __hip_bfloat16 kvT[80][72];

    const int tid = threadIdx.x;
    const int bm = blockIdx.x, bn = blockIdx.y;
    const int kh = bn >> 1;
    const int wave = tid >> 6, lane = tid & 63;
    const int quad = lane >> 4, lr = lane & 15;
    const int wm = (wave >> 1) << 6, wn = (wave & 1) << 6;
    const int b = (gbase + bm * 128) >> 13;               // uniform per block

    // stage kv^T + z (rows 65..79 zero) — ordered by the K-loop's first barrier
    {
        const float* kvsrc = kvf + ((size_t)b * 2 + kh) * 4096;
        for (int i = tid; i < 4096; i += 256) {
            const int m = i >> 6, dh = i & 63;
            kvT[dh][m] = f2bf(kvsrc[i]);
        }
        if (tid < 64) kvT[64][tid] = f2bf(zf[((size_t)b * 2 + kh) * 64 + tid]);
        for (int i = tid; i < 15 * 64; i += 256)
            kvT[65 + (i >> 6)][i & 63] = f2bf(0.0f);
    }

    // ---- stage 1: pq tile ----
    const int srow = (wave << 5) + (lane >> 2);
    const int scol = lane & 3;
    const int sfr  = (srow + (srow >> 2)) & 3;
    const int sofs = ((scol ^ sfr) << 3);

    const __hip_bfloat16* ga0 = h    + (size_t)(bm * 128 + srow) * K + sofs;
    const __hip_bfloat16* gb0 = WQPt + (size_t)(bn * 128 + srow) * K + sofs;
    const __hip_bfloat16* ga1 = ga0 + (size_t)16 * K;
    const __hip_bfloat16* gb1 = gb0 + (size_t)16 * K;
    char* lA0 = As + (wave << 11);
    char* lA1 = lA0 + 1024;
    char* lB0 = Bs + (wave << 11);
    char* lB1 = lB0 + 1024;

    const int fl  = (lr + (lr >> 2)) & 3;
    const int ac  = (quad ^ fl) << 4;
    const char* arp = As + ((wm + lr) << 6) + ac;
    const char* brp = Bs + ((wn + lr) << 6) + ac;

    f32x4 acc[4][4];
    #pragma unroll
    for (int i = 0; i < 4; ++i)
        #pragma unroll
        for (int j = 0; j < 4; ++j)
            #pragma unroll
            for (int r = 0; r < 4; ++r) acc[i][j][r] = 0.0f;

    for (int k0 = 0; k0 < K; k0 += 32) {
        __syncthreads();
        gload_lds16(ga0 + k0, lA0);
        gload_lds16(ga1 + k0, lA1);
        gload_lds16(gb0 + k0, lB0);
        gload_lds16(gb1 + k0, lB1);
        __syncthreads();

        bf16x8 af[4], bfr[4];
        #pragma unroll
        for (int i = 0; i < 4; ++i)
            af[i] = *(const bf16x8*)(arp + i * 1024);
        #pragma unroll
        for (int j = 0; j < 4; ++j)
            bfr[j] = *(const bf16x8*)(brp + j * 1024);
        #pragma unroll
        for (int i = 0; i < 4; ++i)
            #pragma unroll
            for (int j = 0; j < 4; ++j)
                acc[i][j] = __builtin_amdgcn_mfma_f32_16x16x32_bf16(af[i], bfr[j], acc[i][j], 0, 0, 0);
    }

    // P = exp(-|acc|) -> LDS (C-layout write: row = wm+i*16+quad*4+r, col = wn+j*16+lr)
    #pragma unroll
    for (int i = 0; i < 4; ++i)
        #pragma unroll
        for (int j = 0; j < 4; ++j)
            #pragma unroll
            for (int r = 0; r < 4; ++r) {
                const int rl = wm + i * 16 + quad * 4 + r;
                const int cl = wn + j * 16 + lr;
                *(__hip_bfloat16*)(Pl + rl * 272 + cl * 2) = f2bf(expf(-fabsf(acc[i][j][r])));
            }
    __syncthreads();

    // ---- stage 2: attn = (P @ kvT) / (P @ z + eps) ----
    // wave w: rows wm (same), head-local hl = wave&1 (P cols wn..wn+63).
    const int hl = wave & 1;
    f32x4 acc2[4][5];
    #pragma unroll
    for (int i = 0; i < 4; ++i)
        #pragma unroll
        for (int j = 0; j < 5; ++j)
            #pragma unroll
            for (int r = 0; r < 4; ++r) acc2[i][j][r] = 0.0f;

    #pragma unroll
    for (int kk = 0; kk < 2; ++kk) {
        const int kofs = kk * 32 + quad * 8;              // m-offset within head
        bf16x8 af[4], bfr[5];
        #pragma unroll
        for (int i = 0; i < 4; ++i)
            af[i] = *(const bf16x8*)(Pl + (wm + i * 16 + lr) * 272 + (wn + kofs) * 2);
        #pragma unroll
        for (int j = 0; j < 5; ++j)
            bfr[j] = *(const bf16x8*)&kvT[j * 16 + lr][kofs];
        #pragma unroll
        for (int i = 0; i < 4; ++i)
            #pragma unroll
            for (int j = 0; j < 5; ++j)
                acc2[i][j] = __builtin_amdgcn_mfma_f32_16x16x32_bf16(af[i], bfr[j], acc2[i][j], 0, 0, 0);
    }

    const int colb = (bn * 2 + hl) * 64;                  // global head col base
    #pragma unroll
    for (int i = 0; i < 4; ++i) {
        const int rowb = bm * 128 + wm + i * 16 + quad * 4;
        #pragma unroll
        for (int r = 0; r < 4; ++r) {
            const float den = __shfl(acc2[i][4][r], lane & 48, 64);
            const float inv = 1.0f / (den + 1e-6f);
            const size_t base = (size_t)(rowb + r) * 512 + colb;
            #pragma unroll
            for (int j = 0; j < 4; ++j)
                attn[base + j * 16 + lr] = f2bf(acc2[i][j][r] * inv);
        }
    }
}

// ---------------- fused SwiGLU up-GEMM + column-sum (barrier-free, round-3 best) ----------------
// Block = 128 A-rows, FULL K=512 staged once in LDS (128 KiB, XOR-swizzled).
// After one staging sync there are NO barriers: each of 8 waves independently owns
// 256 ffn columns (8 chunks x 32), reading A-fragments from LDS and Wg/Wu fragments
// straight from global (L2-resident, 16 B contiguous per lane). Waves free-run so
// ds_read / VMEM / MFMA overlap naturally. grid = C/128.
// MEASURED CEILING NOTE (rounds 0-5): this variant = 167 us = 823 TF = m97-class
// plain-HIP rate at K=512. Tried & rejected: lockstep 4-phase dbuf (174), m201 phase
// body (176), reg sw-pipeline (spills, 181), 64-row/4-wave occupancy (L2-B-bound, 273).
// B-traffic scales with block count (4 MB L2 per block) -> 128 rows/block is the
// sweet spot where L2-B (59 us/CU) stays under the MFMA floor (66 us/CU).
__global__ __launch_bounds__(512, 2) void ffn8_kernel(
    const __hip_bfloat16* __restrict__ A, const __hip_bfloat16* __restrict__ Bg,
    const __hip_bfloat16* __restrict__ Bu, float* __restrict__ tsum, int gbase)
{
    __shared__ __align__(16) char L[131072];   // A [128 rows][64 slots of 16B], slot^=(row&7)

    const int tid = threadIdx.x;
    const int bm = blockIdx.x;
    const int wave = tid >> 6, lane = tid & 63;
    const int quad = lane >> 4, lr = lane & 15;

    // ---- stage A-tile once: wave w stages rows w, w+8, ... ----
    // LDS linear (dest = base + lane*16); SOURCE slot carries the inverse swizzle.
    {
        const int ss = (lane & 56) | ((lane ^ wave) & 7);
        const __hip_bfloat16* gsrc = A + (size_t)(bm * 128 + wave) * 512 + ss * 8;
        char* ldst = L + wave * 1024;
        #pragma unroll
        for (int i = 0; i < 16; ++i)
            gload_lds16(gsrc + (size_t)i * 8 * 512, ldst + i * 8192);
    }
    asm volatile("s_waitcnt vmcnt(0)" ::: "memory");
    __syncthreads();

    // A-frag (m, ks): row m*16+lr, byte = row*1024 + (((ks*4+quad) ^ (lr&7)) << 4)
    const int x7s = (lr & 7) << 4;
    const char* apq = L + (lr << 10);

    // B: wave owns cols wave*256..+255; fragment row = colbase + ci*32 + cf*16 + lr
    const __hip_bfloat16* pG = Bg + (size_t)(wave * 256 + lr) * 512 + quad * 8;
    const __hip_bfloat16* pU = Bu + (size_t)(wave * 256 + lr) * 512 + quad * 8;

    const int b = (gbase + bm * 128) >> 13;   // 128 | 8192 -> uniform per block

    for (int ci = 0; ci < 8; ++ci) {
        const __hip_bfloat16* pGc = pG + (size_t)ci * 32 * 512;
        const __hip_bfloat16* pUc = pU + (size_t)ci * 32 * 512;

        f32x4 aG[8][2], aU[8][2];
        #pragma unroll
        for (int m = 0; m < 8; ++m)
            #pragma unroll
            for (int c = 0; c < 2; ++c)
                #pragma unroll
                for (int r = 0; r < 4; ++r) { aG[m][c][r] = 0.0f; aU[m][c][r] = 0.0f; }

        #pragma unroll 2
        for (int ks = 0; ks < 16; ++ks) {
            // swizzled 16B-slot offset for this ks (shared by all 8 row-frags)
            const int so = ((ks << 6) | (quad << 4)) ^ x7s;
            bf16x8 af[8];
            #pragma unroll
            for (int m = 0; m < 8; ++m)
                af[m] = *(const bf16x8*)(apq + m * 16384 + so);
            bf16x8 bg0 = *(const bf16x8*)(pGc + ks * 32);
            bf16x8 bg1 = *(const bf16x8*)(pGc + 16 * 512 + ks * 32);
            bf16x8 bu0 = *(const bf16x8*)(pUc + ks * 32);
            bf16x8 bu1 = *(const bf16x8*)(pUc + 16 * 512 + ks * 32);
            #pragma unroll
            for (int m = 0; m < 8; ++m) {
                aG[m][0] = __builtin_amdgcn_mfma_f32_16x16x32_bf16(af[m], bg0, aG[m][0], 0, 0, 0);
                aG[m][1] = __builtin_amdgcn_mfma_f32_16x16x32_bf16(af[m], bg1, aG[m][1], 0, 0, 0);
                aU[m][0] = __builtin_amdgcn_mfma_f32_16x16x32_bf16(af[m], bu0, aU[m][0], 0, 0, 0);
                aU[m][1] = __builtin_amdgcn_mfma_f32_16x16x32_bf16(af[m], bu1, aU[m][1], 0, 0, 0);
            }
        }

        // ---- chunk epilogue: colsum of silu(g)*u over this block's 128 rows ----
        #pragma unroll
        for (int c = 0; c < 2; ++c) {
            float s = 0.f;
            #pragma unroll
            for (int m = 0; m < 8; ++m)
                #pragma unroll
                for (int r = 0; r < 4; ++r) {
                    const float g = aG[m][c][r];
                    s += (g / (1.0f + expf(-g))) * aU[m][c][r];
                }
            s += __shfl_xor(s, 16, 64);
            s += __shfl_xor(s, 32, 64);
            if (quad == 0)
                atomicAdd(&tsum[b * 2048 + wave * 256 + ci * 32 + c * 16 + lr], s);
        }
    }
}

// ---------------- pooled[b][:] += tsum[b][:] @ Wd  (k-split parallel) ----------------
__global__ __launch_bounds__(256) void ffn_pool_kernel(
    const float* __restrict__ tsum, const void* __restrict__ Wd,
    float* __restrict__ pooled, const int* __restrict__ flag)
{
    __shared__ float ts[8][64];
    const int f = *flag;
    const int k0 = blockIdx.x * 64;
    const int t = threadIdx.x;
    for (int i = t; i < 512; i += 256)
        ts[i >> 6][i & 63] = tsum[(i >> 6) * 2048 + k0 + (i & 63)];
    __syncthreads();

    float acc0[8] = {}, acc1[8] = {};
    for (int kk = 0; kk < 64; ++kk) {
        const size_t krow = (size_t)(k0 + kk) * 512;
        const float w0 = loadElem(Wd, krow + t, f);
        const float w1 = loadElem(Wd, krow + t + 256, f);
        #pragma unroll
        for (int b = 0; b < 8; ++b) {
            acc0[b] += ts[b][kk] * w0;
            acc1[b] += ts[b][kk] * w1;
        }
    }
    #pragma unroll
    for (int b = 0; b < 8; ++b) {
        atomicAdd(&pooled[b * 512 + t], acc0[b]);
        atomicAdd(&pooled[b * 512 + t + 256], acc1[b]);
    }
}

// ---------------- kv / z global-state reduction (pkv [C][256] input) ----------------
__global__ __launch_bounds__(256) void kv_z_kernel(
    const __hip_bfloat16* __restrict__ pkv,
    float* __restrict__ kv, float* __restrict__ z, int gbase, int nrows)
{
    __shared__ float pks[8][64], vs[8][64];
    const int slab = blockIdx.x, kh = blockIdx.y;
    const int b = (gbase + slab * nrows) >> 13;
    const int tid = threadIdx.x;
    const int tm = (tid & 15) << 2, tdh = (tid >> 4) << 2;
    const int lss = tid >> 5, lmm = (tid & 31) << 1;

    float acc[4][4] = {};
    float zacc[4] = {};
    for (int sb = 0; sb < nrows; sb += 8) {
        __syncthreads();
        {
            const size_t n = (size_t)slab * nrows + sb + lss;
            const __hip_bfloat16* pr = pkv + n * 256 + kh * 64 + lmm;
            const __hip_bfloat16* vr = pkv + n * 256 + 128 + kh * 64 + lmm;
            pks[lss][lmm]     = bf2f(pr[0]);
            pks[lss][lmm + 1] = bf2f(pr[1]);
            vs[lss][lmm]      = bf2f(vr[0]);
            vs[lss][lmm + 1]  = bf2f(vr[1]);
        }
        __syncthreads();
        #pragma unroll
        for (int ss = 0; ss < 8; ++ss) {
            f32x4 p = *(const f32x4*)&pks[ss][tm];
            f32x4 w = *(const f32x4*)&vs[ss][tdh];
            #pragma unroll
            for (int i = 0; i < 4; ++i)
                #pragma unroll
                for (int j = 0; j < 4; ++j)
                    acc[i][j] += p[i] * w[j];
            if ((tid >> 4) == 0) {
                #pragma unroll
                for (int i = 0; i < 4; ++i) zacc[i] += p[i];
            }
        }
    }
    #pragma unroll
    for (int i = 0; i < 4; ++i)
        #pragma unroll
        for (int j = 0; j < 4; ++j)
            atomicAdd(&kv[(((size_t)b * 2 + kh) * 64 + tm + i) * 64 + tdh + j], acc[i][j]);
    if ((tid >> 4) == 0) {
        #pragma unroll
        for (int i = 0; i < 4; ++i)
            atomicAdd(&z[((size_t)b * 2 + kh) * 64 + tm + i], zacc[i]);
    }
}

// ---------------- classifier head ----------------
__global__ __launch_bounds__(256) void head_kernel(
    const float* __restrict__ pooled, const void* __restrict__ Wc,
    const void* __restrict__ bc, void* __restrict__ out, const int* __restrict__ flag)
{
    const int f = *flag;
    const int t = threadIdx.x;
    const int grp = t >> 4, ln = t & 15;
    const int b = grp >> 1, c = grp & 1;
    float p = 0.f;
    for (int d = ln; d < 512; d += 16)
        p += pooled[b * 512 + d] * loadElem(Wc, (size_t)d * 2 + c, f);
    #pragma unroll
    for (int off = 8; off; off >>= 1) p += __shfl_xor(p, off, 64);
    if (ln == 0) {
        const float val = p * (1.0f / 8192.0f) + loadElem(bc, c, f);
        if (f) ((float*)out)[b * 2 + c] = val;
        else   ((__hip_bfloat16*)out)[b * 2 + c] = f2bf(val);
    }
}

// ---------------- launch ----------------
extern "C" void kernel_launch(void* const* d_in, const int* in_sizes, int n_in,
                              void* d_out, int out_size, void* d_ws, size_t ws_size,
                              hipStream_t stream)
{
    const int* ids   = (const int*)d_in[0];
    const void* emb  = d_in[1];
    const void* Wq   = d_in[2];
    const void* Wk   = d_in[3];
    const void* Wv   = d_in[4];
    const void* Wph  = d_in[5];
    const void* Wo   = d_in[6];
    const void* g1   = d_in[7];
    const void* g2   = d_in[8];
    const void* Wg   = d_in[9];
    const void* Wu   = d_in[10];
    const void* Wd   = d_in[11];
    const void* Wc   = d_in[12];
    const void* bc   = d_in[13];

    char* ws = (char*)d_ws;
    __hip_bfloat16* WQPt  = (__hip_bfloat16*)(ws + OFF_WQPT);
    __hip_bfloat16* WKPt  = (__hip_bfloat16*)(ws + OFF_WKPT);  // [WKPt|WvT] = [256][512]
    __hip_bfloat16* WvT   = (__hip_bfloat16*)(ws + OFF_WVT);
    __hip_bfloat16* WoT   = (__hip_bfloat16*)(ws + OFF_WOT);
    __hip_bfloat16* WgT   = (__hip_bfloat16*)(ws + OFF_WGT);
    __hip_bfloat16* WuT   = (__hip_bfloat16*)(ws + OFF_WUT);
    float*          kv    = (float*)(ws + OFF_KV);
    float*          z     = (float*)(ws + OFF_Z);
    float*          pooled= (float*)(ws + OFF_POOL);
    float*          tsum  = (float*)(ws + OFF_TSUM);
    int*            flag  = (int*)(ws + OFF_FLAG);
    __hip_bfloat16* hall  = (__hip_bfloat16*)(ws + OFF_H);     // bf16 [65536][512], persistent

    // ---- adaptive chunk: largest power-of-2 C in [256, 65536] that fits ws ----
    // C=65536 (NC=1) halves the per-chunk launch count when ws >= ~308 MB.
    int C = 65536;
    while (C > 256 && CHUNKBASE + PERTOK * (size_t)C > ws_size) C >>= 1;
    const int NC = NTOK / C;

    char* cb = ws + CHUNKBASE;
    float*          xf   = (float*)cb;                                  // f32  [C][512]
    __hip_bfloat16* attn = (__hip_bfloat16*)(cb + (size_t)C * 2048);    // bf16 [C][512]
    __hip_bfloat16* pkv  = (__hip_bfloat16*)(cb + (size_t)C * 3072);    // bf16 [C][256]

    detect_kernel<<<1, 128, 0, stream>>>((const unsigned int*)Wph, flag);
    zero_kernel<<<(ZERO_FLOATS + 255) / 256, 256, 0, stream>>>(kv, ZERO_FLOATS);

    // weight prep
    fuse_phi_kernel<<<1024, 256, 0, stream>>>(Wq, Wph, WQPt, 512, flag);
    fuse_phi_kernel<<<256, 256, 0, stream>>>(Wk, Wph, WKPt, 128, flag);
    transpose_kernel<<<dim3(128 / 32, 512 / 32), 256, 0, stream>>>(Wv, WvT, 512, 128, flag);
    transpose_kernel<<<dim3(512 / 32, 512 / 32), 256, 0, stream>>>(Wo, WoT, 512, 512, flag);
    transpose_kernel<<<dim3(2048 / 32, 512 / 32), 256, 0, stream>>>(Wg, WgT, 512, 2048, flag);
    transpose_kernel<<<dim3(2048 / 32, 512 / 32), 256, 0, stream>>>(Wu, WuT, 512, 2048, flag);

    // ---- pass A: per chunk h -> pk|v -> accumulate global kv / z ----
    // h is written to its persistent slot so pass B reuses it (no re-gather/re-norm).
    for (int c = 0; c < NC; ++c) {
        const int g0 = c * C;
        __hip_bfloat16* hc = hall + (size_t)g0 * 512;
        embed_rms_kernel<<<C / 4, 256, 0, stream>>>(ids + g0, emb, g1, hc, flag);
        gemm128_kernel<8><<<dim3(C / 128, 2), 256, 0, stream>>>(
            hc, WKPt, nullptr, pkv, nullptr, nullptr, nullptr, flag, g0, 512);
        kv_z_kernel<<<dim3(C / 128, 2), 256, 0, stream>>>(pkv, kv, z, g0, 128);
    }

    // ---- pass B: per chunk (stored h) -> fused pq+mix -> Wo(+emb residual,+pool) -> rms -> ffn ----
    for (int c = 0; c < NC; ++c) {
        const int g0 = c * C;
        __hip_bfloat16* hc = hall + (size_t)g0 * 512;
        pq_mix_kernel<<<dim3(C / 128, 4), 256, 0, stream>>>(
            hc, WQPt, kv, z, attn, g0, 512);
        gemm128_kernel<7><<<dim3(C / 128, 4), 256, 0, stream>>>(
            attn, WoT, xf, nullptr, pooled, ids + g0, emb, flag, g0, 512);
        rms2_kernel<<<C / 4, 256, 0, stream>>>(xf, g2, hc, flag);   // overwrites hc with h2
        ffn8_kernel<<<C / 128, 512, 0, stream>>>(hc, WgT, WuT, tsum, g0);
    }

    // pooled += tsum @ Wd  (exact: pooling is linear; k-split parallel)
    ffn_pool_kernel<<<32, 256, 0, stream>>>(tsum, Wd, pooled, flag);

    head_kernel<<<1, 256, 0, stream>>>(pooled, Wc, bc, d_out, flag);
}

// Round 7
// 809.538 us; speedup vs baseline: 1.3859x; 1.1234x over previous
//
#include <hip/hip_runtime.h>
#include <hip/hip_bf16.h>
#include <math.h>

// ---------------- types / helpers ----------------
typedef __attribute__((ext_vector_type(8))) short bf16x8;
typedef __attribute__((ext_vector_type(4))) float f32x4;

#define DEV static __device__ __forceinline__
#define AS1 __attribute__((address_space(1)))
#define AS3 __attribute__((address_space(3)))

DEV float bf2f(__hip_bfloat16 v) { return __bfloat162float(v); }
DEV __hip_bfloat16 f2bf(float f) { return __float2bfloat16(f); }
DEV float us2f(unsigned short u) { return __uint_as_float(((unsigned int)u) << 16); }
DEV unsigned short f2us(float f) {
    __hip_bfloat16 b = __float2bfloat16(f);
    return *(unsigned short*)&b;
}

// async global->LDS, 16 B per lane (LDS dst = wave-uniform base + lane*16)
DEV void gload_lds16(const void* g, void* l) {
    __builtin_amdgcn_global_load_lds((const AS1 unsigned int*)g,
                                     (AS3 unsigned int*)l, 16, 0, 0);
}

// load 8 consecutive floats from an input tensor that is either f32 or bf16
DEV void load8(const void* p, size_t off, int f32m, float* o) {
    if (f32m) {
        const float4* r = (const float4*)((const float*)p + off);
        float4 A = r[0], B = r[1];
        o[0] = A.x; o[1] = A.y; o[2] = A.z; o[3] = A.w;
        o[4] = B.x; o[5] = B.y; o[6] = B.z; o[7] = B.w;
    } else {
        const ushort4* r = (const ushort4*)((const __hip_bfloat16*)p + off);
        ushort4 A = r[0], B = r[1];
        o[0] = us2f(A.x); o[1] = us2f(A.y); o[2] = us2f(A.z); o[3] = us2f(A.w);
        o[4] = us2f(B.x); o[5] = us2f(B.y); o[6] = us2f(B.z); o[7] = us2f(B.w);
    }
}

DEV float loadElem(const void* p, size_t idx, int f32m) {
    return f32m ? ((const float*)p)[idx] : bf2f(((const __hip_bfloat16*)p)[idx]);
}

// ---------------- problem constants ----------------
// B=8 S=8192 D=512 H=8 HK=2 DH=64 M=64 DFF=2048 NCLS=2 G=4
constexpr int NTOK = 65536;   // 8*8192

// ---------------- persistent ws layout (bytes) ----------------
constexpr size_t OFF_WQPT = 0;                       // bf16 [512][512]  (Wq@Wphi)^T
constexpr size_t OFF_WKPT = OFF_WQPT + 524288ull;    // bf16 [128][512]  (Wk@Wphi)^T   } contiguous:
constexpr size_t OFF_WVT  = OFF_WKPT + 131072ull;    // bf16 [128][512]  Wv^T          } [256][512]
constexpr size_t OFF_WOT  = OFF_WVT  + 131072ull;    // bf16 [512][512]  Wo^T
constexpr size_t OFF_WGT  = OFF_WOT  + 524288ull;    // bf16 [2048][512] Wg^T
constexpr size_t OFF_WUT  = OFF_WGT  + 2097152ull;   // bf16 [2048][512] Wu^T
constexpr size_t OFF_KV   = OFF_WUT  + 2097152ull;   // f32  [8][2][64][64]
constexpr size_t OFF_Z    = OFF_KV   + 262144ull;    // f32  [8][2][64]
constexpr size_t OFF_POOL = OFF_Z    + 4096ull;      // f32  [8][512]
constexpr size_t OFF_TSUM = OFF_POOL + 16384ull;     // f32  [8][2048]  col-sums of FFN t
constexpr size_t OFF_FLAG = OFF_TSUM + 65536ull;     // int  dtype flag (1 = f32 inputs)
constexpr size_t PERSIST  = OFF_FLAG + 256ull;
// h is persistent for ALL tokens (pass A writes, pass B's pq_mix reads it)
constexpr size_t OFF_H    = PERSIST;                 // bf16 [65536][512] = 64 MB
constexpr size_t CHUNKBASE = OFF_H + 67108864ull;
constexpr int    ZERO_FLOATS = (262144 + 4096 + 16384 + 65536) / 4;  // kv+z+pooled+tsum
// per-token chunk bytes: attn 1024 + pkv 512 = 1536  (xf ELIMINATED by wo_ffn fusion)
constexpr size_t PERTOK = 1536ull;
// C=65536 now needs 69.7 MB + 100.7 MB = 170.4 MB < 234.4 MB proven -> NC=1 guaranteed.

// ---------------- dtype detection ----------------
__global__ __launch_bounds__(128) void detect_kernel(
    const unsigned int* __restrict__ w, int* __restrict__ flag)
{
    __shared__ int cnt;
    if (threadIdx.x == 0) cnt = 0;
    __syncthreads();
    unsigned int v = w[threadIdx.x];
    float a = fabsf(us2f((unsigned short)(v & 0xFFFFu)));
    if (a >= 0.0625f && a <= 8.0f) atomicAdd(&cnt, 1);
    __syncthreads();
    if (threadIdx.x == 0) *flag = (cnt < 64) ? 1 : 0;
}

// ---------------- tiny init ----------------
__global__ __launch_bounds__(256) void zero_kernel(float* __restrict__ p, int n)
{
    int i = blockIdx.x * 256 + threadIdx.x;
    if (i < n) p[i] = 0.0f;
}

// ---------------- weight prep ----------------
// outT[hm][d] = sum_dh W[d][h*64+dh] * Wphi[dh][m]   (hm = h*64+m), row-major [nh*64][512]
__global__ __launch_bounds__(256) void fuse_phi_kernel(
    const void* __restrict__ W, const void* __restrict__ Wphi,
    __hip_bfloat16* __restrict__ outT, int wld, const int* __restrict__ flag)
{
    const int f = *flag;
    int o = blockIdx.x * 256 + threadIdx.x;   // o = hm*512 + d
    int hm = o >> 9, d = o & 511;
    int h = hm >> 6, m = hm & 63;
    float acc = 0.f;
    if (f) {
        const float* Wf = (const float*)W;
        const float* Pf = (const float*)Wphi;
        #pragma unroll 8
        for (int dh = 0; dh < 64; ++dh)
            acc += Wf[(size_t)d * wld + h * 64 + dh] * Pf[dh * 64 + m];
    } else {
        const __hip_bfloat16* Wb = (const __hip_bfloat16*)W;
        const __hip_bfloat16* Pb = (const __hip_bfloat16*)Wphi;
        #pragma unroll 8
        for (int dh = 0; dh < 64; ++dh)
            acc += bf2f(Wb[(size_t)d * wld + h * 64 + dh]) * bf2f(Pb[dh * 64 + m]);
    }
    outT[o] = f2bf(acc);
}

// dst[Ccols][R] = src[R][Ccols]^T, LDS-tiled 32x32
__global__ __launch_bounds__(256) void transpose_kernel(
    const void* __restrict__ src, __hip_bfloat16* __restrict__ dst, int R, int Ccols,
    const int* __restrict__ flag)
{
    __shared__ float tile[32][33];
    const int f = *flag;
    const int tx = threadIdx.x & 31, ty = threadIdx.x >> 5;   // 32 x 8
    const int c0 = blockIdx.x * 32, r0 = blockIdx.y * 32;
    #pragma unroll
    for (int k = 0; k < 4; ++k) {
        const int rl = ty + k * 8;
        tile[rl][tx] = loadElem(src, (size_t)(r0 + rl) * Ccols + c0 + tx, f);
    }
    __syncthreads();
    #pragma unroll
    for (int k = 0; k < 4; ++k) {
        const int cl = ty + k * 8;
        dst[(size_t)(c0 + cl) * R + r0 + tx] = f2bf(tile[tx][cl]);
    }
}

// ---------------- embedding gather + rmsnorm -> h (wave per row) ----------------
__global__ __launch_bounds__(256) void embed_rms_kernel(
    const int* __restrict__ ids, const void* __restrict__ emb,
    const void* __restrict__ g1, __hip_bfloat16* __restrict__ h,
    const int* __restrict__ flag)
{
    const int f = *flag;
    const int n = blockIdx.x * 4 + (threadIdx.x >> 6);   // local row in chunk
    const int lane = threadIdx.x & 63;
    const int id = ids[n];
    float x[8];
    load8(emb, (size_t)id * 512 + lane * 8, f, x);
    float ss = 0.f;
    #pragma unroll
    for (int i = 0; i < 8; ++i) ss += x[i] * x[i];
    #pragma unroll
    for (int off = 32; off; off >>= 1) ss += __shfl_xor(ss, off, 64);
    const float scale = rsqrtf(ss * (1.0f / 512.0f) + 1e-6f);
    float gv[8];
    load8(g1, (size_t)lane * 8, f, gv);
    ushort4 h0, h1;
    h0.x = f2us(x[0] * scale * gv[0]); h0.y = f2us(x[1] * scale * gv[1]);
    h0.z = f2us(x[2] * scale * gv[2]); h0.w = f2us(x[3] * scale * gv[3]);
    h1.x = f2us(x[4] * scale * gv[4]); h1.y = f2us(x[5] * scale * gv[5]);
    h1.z = f2us(x[6] * scale * gv[6]); h1.w = f2us(x[7] * scale * gv[7]);
    ushort4* ho = (ushort4*)(h + (size_t)n * 512 + lane * 8);
    ho[0] = h0; ho[1] = h1;
}

// ---------------- MFMA GEMM: C[M,N] = A[M,K] @ Bt[N,K]^T ----------------
// m97 structure: 128x128 tile, BK=32, global_load_lds width-16 staging, XOR swizzle.
// MODE 8: pk|v epilogue: bn==0 -> pkv cols 0..127 = exp(-|acc|); bn==1 -> cols 128..255 = acc
template<int MODE>
__global__ __launch_bounds__(256) void gemm128_kernel(
    const __hip_bfloat16* __restrict__ A, const __hip_bfloat16* __restrict__ Bt,
    __hip_bfloat16* __restrict__ Cout2, const int* __restrict__ flag, int gbase, int K)
{
    __shared__ __align__(16) char As[8192];   // bf16 [128 rows][32 k], swizzled chunks
    __shared__ __align__(16) char Bs[8192];

    const int tid = threadIdx.x;
    const int bm = blockIdx.x, bn = blockIdx.y;
    const int wave = tid >> 6, lane = tid & 63;
    const int quad = lane >> 4, lr = lane & 15;
    const int wm = (wave >> 1) << 6, wn = (wave & 1) << 6;

    const int srow = (wave << 5) + (lane >> 2);
    const int scol = lane & 3;
    const int sfr  = (srow + (srow >> 2)) & 3;
    const int sofs = ((scol ^ sfr) << 3);

    const __hip_bfloat16* ga0 = A  + (size_t)(bm * 128 + srow) * K + sofs;
    const __hip_bfloat16* gb0 = Bt + (size_t)(bn * 128 + srow) * K + sofs;
    const __hip_bfloat16* ga1 = ga0 + (size_t)16 * K;
    const __hip_bfloat16* gb1 = gb0 + (size_t)16 * K;
    char* lA0 = As + (wave << 11);
    char* lA1 = lA0 + 1024;
    char* lB0 = Bs + (wave << 11);
    char* lB1 = lB0 + 1024;

    const int fl  = (lr + (lr >> 2)) & 3;
    const int ac  = (quad ^ fl) << 4;
    const char* arp = As + ((wm + lr) << 6) + ac;
    const char* brp = Bs + ((wn + lr) << 6) + ac;

    f32x4 acc[4][4];
    #pragma unroll
    for (int i = 0; i < 4; ++i)
        #pragma unroll
        for (int j = 0; j < 4; ++j)
            #pragma unroll
            for (int r = 0; r < 4; ++r) acc[i][j][r] = 0.0f;

    for (int k0 = 0; k0 < K; k0 += 32) {
        __syncthreads();
        gload_lds16(ga0 + k0, lA0);
        gload_lds16(ga1 + k0, lA1);
        gload_lds16(gb0 + k0, lB0);
        gload_lds16(gb1 + k0, lB1);
        __syncthreads();

        bf16x8 af[4], bfr[4];
        #pragma unroll
        for (int i = 0; i < 4; ++i)
            af[i] = *(const bf16x8*)(arp + i * 1024);
        #pragma unroll
        for (int j = 0; j < 4; ++j)
            bfr[j] = *(const bf16x8*)(brp + j * 1024);
        #pragma unroll
        for (int i = 0; i < 4; ++i)
            #pragma unroll
            for (int j = 0; j < 4; ++j)
                acc[i][j] = __builtin_amdgcn_mfma_f32_16x16x32_bf16(af[i], bfr[j], acc[i][j], 0, 0, 0);
    }

    // C/D layout: col = lane&15, row = quad*4 + reg  [m89/m91]
    const int col0 = bn * 128 + wn + lr;

    // MODE 8: pk|v
    const int row0 = bm * 128 + wm + quad * 4;
    #pragma unroll
    for (int i = 0; i < 4; ++i)
        #pragma unroll
        for (int j = 0; j < 4; ++j) {
            const int col = col0 + j * 16;   // 0..255
            #pragma unroll
            for (int r = 0; r < 4; ++r) {
                const int row = row0 + i * 16 + r;
                const float v = acc[i][j][r];
                Cout2[(size_t)row * 256 + col] = f2bf(bn == 0 ? expf(-fabsf(v)) : v);
            }
        }
}

// ---------------- fused pq-GEMM + attention mix ----------------
// Block (bm, bn): rows bm*128..+127, heads {2bn, 2bn+1} (kh = bn>>1).
// Stage 1: P = exp(-|h @ WQPt^T|) tile 128x128 (m97 K-loop) -> LDS (bf16).
// Stage 2: attn = (P @ kvT) / (P @ z + eps)  (m120 layout round-trip).
__global__ __launch_bounds__(256, 2) void pq_mix_kernel(
    const __hip_bfloat16* __restrict__ h, const __hip_bfloat16* __restrict__ WQPt,
    const float* __restrict__ kvf, const float* __restrict__ zf,
    __hip_bfloat16* __restrict__ attn, int gbase, int K)
{
    __shared__ __align__(16) char As[8192];
    __shared__ __align__(16) char Bs[8192];
    __shared__ __align__(16) char Pl[128 * 272];          // bf16 [128][136] (8-col pad)
    __shared__ __align__(16) __hip_bfloat16 kvT[80][72];

    const int tid = threadIdx.x;
    const int bm = blockIdx.x, bn = blockIdx.y;
    const int kh = bn >> 1;
    const int wave = tid >> 6, lane = tid & 63;
    const int quad = lane >> 4, lr = lane & 15;
    const int wm = (wave >> 1) << 6, wn = (wave & 1) << 6;
    const int b = (gbase + bm * 128) >> 13;               // uniform per block

    // stage kv^T + z (rows 65..79 zero) — ordered by the K-loop's first barrier
    {
        const float* kvsrc = kvf + ((size_t)b * 2 + kh) * 4096;
        for (int i = tid; i < 4096; i += 256) {
            const int m = i >> 6, dh = i & 63;
            kvT[dh][m] = f2bf(kvsrc[i]);
        }
        if (tid < 64) kvT[64][tid] = f2bf(zf[((size_t)b * 2 + kh) * 64 + tid]);
        for (int i = tid; i < 15 * 64; i += 256)
            kvT[65 + (i >> 6)][i & 63] = f2bf(0.0f);
    }

    // ---- stage 1: pq tile ----
    const int srow = (wave << 5) + (lane >> 2);
    const int scol = lane & 3;
    const int sfr  = (srow + (srow >> 2)) & 3;
    const int sofs = ((scol ^ sfr) << 3);

    const __hip_bfloat16* ga0 = h    + (size_t)(bm * 128 + srow) * K + sofs;
    const __hip_bfloat16* gb0 = WQPt + (size_t)(bn * 128 + srow) * K + sofs;
    const __hip_bfloat16* ga1 = ga0 + (size_t)16 * K;
    const __hip_bfloat16* gb1 = gb0 + (size_t)16 * K;
    char* lA0 = As + (wave << 11);
    char* lA1 = lA0 + 1024;
    char* lB0 = Bs + (wave << 11);
    char* lB1 = lB0 + 1024;

    const int fl  = (lr + (lr >> 2)) & 3;
    const int ac  = (quad ^ fl) << 4;
    const char* arp = As + ((wm + lr) << 6) + ac;
    const char* brp = Bs + ((wn + lr) << 6) + ac;

    f32x4 acc[4][4];
    #pragma unroll
    for (int i = 0; i < 4; ++i)
        #pragma unroll
        for (int j = 0; j < 4; ++j)
            #pragma unroll
            for (int r = 0; r < 4; ++r) acc[i][j][r] = 0.0f;

    for (int k0 = 0; k0 < K; k0 += 32) {
        __syncthreads();
        gload_lds16(ga0 + k0, lA0);
        gload_lds16(ga1 + k0, lA1);
        gload_lds16(gb0 + k0, lB0);
        gload_lds16(gb1 + k0, lB1);
        __syncthreads();

        bf16x8 af[4], bfr[4];
        #pragma unroll
        for (int i = 0; i < 4; ++i)
            af[i] = *(const bf16x8*)(arp + i * 1024);
        #pragma unroll
        for (int j = 0; j < 4; ++j)
            bfr[j] = *(const bf16x8*)(brp + j * 1024);
        #pragma unroll
        for (int i = 0; i < 4; ++i)
            #pragma unroll
            for (int j = 0; j < 4; ++j)
                acc[i][j] = __builtin_amdgcn_mfma_f32_16x16x32_bf16(af[i], bfr[j], acc[i][j], 0, 0, 0);
    }

    // P = exp(-|acc|) -> LDS (C-layout write: row = wm+i*16+quad*4+r, col = wn+j*16+lr)
    #pragma unroll
    for (int i = 0; i < 4; ++i)
        #pragma unroll
        for (int j = 0; j < 4; ++j)
            #pragma unroll
            for (int r = 0; r < 4; ++r) {
                const int rl = wm + i * 16 + quad * 4 + r;
                const int cl = wn + j * 16 + lr;
                *(__hip_bfloat16*)(Pl + rl * 272 + cl * 2) = f2bf(expf(-fabsf(acc[i][j][r])));
            }
    __syncthreads();

    // ---- stage 2: attn = (P @ kvT) / (P @ z + eps) ----
    // wave w: rows wm (same), head-local hl = wave&1 (P cols wn..wn+63).
    const int hl = wave & 1;
    f32x4 acc2[4][5];
    #pragma unroll
    for (int i = 0; i < 4; ++i)
        #pragma unroll
        for (int j = 0; j < 5; ++j)
            #pragma unroll
            for (int r = 0; r < 4; ++r) acc2[i][j][r] = 0.0f;

    #pragma unroll
    for (int kk = 0; kk < 2; ++kk) {
        const int kofs = kk * 32 + quad * 8;              // m-offset within head
        bf16x8 af[4], bfr[5];
        #pragma unroll
        for (int i = 0; i < 4; ++i)
            af[i] = *(const bf16x8*)(Pl + (wm + i * 16 + lr) * 272 + (wn + kofs) * 2);
        #pragma unroll
        for (int j = 0; j < 5; ++j)
            bfr[j] = *(const bf16x8*)&kvT[j * 16 + lr][kofs];
        #pragma unroll
        for (int i = 0; i < 4; ++i)
            #pragma unroll
            for (int j = 0; j < 5; ++j)
                acc2[i][j] = __builtin_amdgcn_mfma_f32_16x16x32_bf16(af[i], bfr[j], acc2[i][j], 0, 0, 0);
    }

    const int colb = (bn * 2 + hl) * 64;                  // global head col base
    #pragma unroll
    for (int i = 0; i < 4; ++i) {
        const int rowb = bm * 128 + wm + i * 16 + quad * 4;
        #pragma unroll
        for (int r = 0; r < 4; ++r) {
            const float den = __shfl(acc2[i][4][r], lane & 48, 64);
            const float inv = 1.0f / (den + 1e-6f);
            const size_t base = (size_t)(rowb + r) * 512 + colb;
            #pragma unroll
            for (int j = 0; j < 4; ++j)
                attn[base + j * 16 + lr] = f2bf(acc2[i][j][r] * inv);
        }
    }
}

// ---------------- MEGA-FUSED: attn@Wo + emb residual + pool + rmsnorm + SwiGLU FFN ----------------
// Block = 128 token rows, 512 threads (8 waves). Eliminates xf, rms2, and the h2
// global round-trip (saves ~590 MB traffic + 2 dispatches vs g7+rms2+ffn8).
// Phase 1: stage attn tile [128][512] bf16 in LDS (XOR-swizzled, ffn8-proven staging).
// Phase 2: Wo-GEMM ffn8-style: wave owns 64 out-cols, B=WoT from global (L2, 0.5 MB).
// Phase 3: x = emb residual + acc (in-place in acc regs); pool colsums; rmsnorm stats
//          via deterministic per-wave rssW + tree reduce (no atomics).
// Phase 4: h2 = x*scale*g2 written back into the SAME LDS tile (swizzled scalar writes).
// Phase 5: exact ffn8 body (barrier-free K=512, B=WgT/WuT from global) + tsum drain.
__global__ __launch_bounds__(512, 2) void wo_ffn_kernel(
    const __hip_bfloat16* __restrict__ attn, const __hip_bfloat16* __restrict__ WoT,
    const __hip_bfloat16* __restrict__ Bg, const __hip_bfloat16* __restrict__ Bu,
    const int* __restrict__ ids, const void* __restrict__ emb, const void* __restrict__ g2,
    float* __restrict__ pooled, float* __restrict__ tsum,
    const int* __restrict__ flag, int gbase)
{
    __shared__ __align__(16) char L[131072];   // [128 rows][64 slots of 16B], slot^=(row&7)
    __shared__ int   idsL[128];
    __shared__ float rssW[8][128];             // per-wave row sum-of-squares partials
    __shared__ float scaleL[128];

    const int tid = threadIdx.x;
    const int bm = blockIdx.x;
    const int wave = tid >> 6, lane = tid & 63;
    const int quad = lane >> 4, lr = lane & 15;
    const int f = *flag;
    const int b = (gbase + bm * 128) >> 13;    // 128 | 8192 -> uniform per block

    if (tid < 128) idsL[tid] = ids[bm * 128 + tid];

    // ---- phase 1: stage attn tile (wave w stages rows w, w+8, ..., w+120) ----
    {
        const int ss = (lane & 56) | ((lane ^ wave) & 7);
        const __hip_bfloat16* gsrc = attn + (size_t)(bm * 128 + wave) * 512 + ss * 8;
        char* ldst = L + wave * 1024;
        #pragma unroll
        for (int i = 0; i < 16; ++i)
            gload_lds16(gsrc + (size_t)i * 8 * 512, ldst + i * 8192);
    }
    asm volatile("s_waitcnt vmcnt(0)" ::: "memory");
    __syncthreads();

    const int x7s = (lr & 7) << 4;
    const char* apq = L + (lr << 10);

    // ---- phase 2: Wo-GEMM. wave owns out cols wave*64 .. +63 ----
    {
        const __hip_bfloat16* pW = WoT + (size_t)(wave * 64 + lr) * 512 + quad * 8;
        f32x4 acc[8][4];
        #pragma unroll
        for (int m = 0; m < 8; ++m)
            #pragma unroll
            for (int c = 0; c < 4; ++c)
                #pragma unroll
                for (int r = 0; r < 4; ++r) acc[m][c][r] = 0.0f;

        #pragma unroll 2
        for (int ks = 0; ks < 16; ++ks) {
            const int so = ((ks << 6) | (quad << 4)) ^ x7s;
            bf16x8 af[8];
            #pragma unroll
            for (int m = 0; m < 8; ++m)
                af[m] = *(const bf16x8*)(apq + m * 16384 + so);
            bf16x8 bw[4];
            #pragma unroll
            for (int c = 0; c < 4; ++c)
                bw[c] = *(const bf16x8*)(pW + (size_t)c * 16 * 512 + ks * 32);
            #pragma unroll
            for (int m = 0; m < 8; ++m)
                #pragma unroll
                for (int c = 0; c < 4; ++c)
                    acc[m][c] = __builtin_amdgcn_mfma_f32_16x16x32_bf16(af[m], bw[c], acc[m][c], 0, 0, 0);
        }
        __syncthreads();   // all tile reads done; tile will be overwritten in phase 4

        // ---- phase 3: residual (in-place) + pool colsums + row sum-of-squares ----
        #pragma unroll
        for (int c = 0; c < 4; ++c) {
            const int col = wave * 64 + c * 16 + lr;
            float s = 0.f;
            #pragma unroll
            for (int m = 0; m < 8; ++m)
                #pragma unroll
                for (int r = 0; r < 4; ++r) {
                    const int row = m * 16 + quad * 4 + r;
                    const float e = loadElem(emb, (size_t)idsL[row] * 512 + col, f);
                    acc[m][c][r] += e;
                    s += acc[m][c][r];
                }
            s += __shfl_xor(s, 16, 64);
            s += __shfl_xor(s, 32, 64);
            if (quad == 0) atomicAdd(&pooled[b * 512 + col], s);
        }
        #pragma unroll
        for (int m = 0; m < 8; ++m)
            #pragma unroll
            for (int r = 0; r < 4; ++r) {
                float q = 0.f;
                #pragma unroll
                for (int c = 0; c < 4; ++c) q += acc[m][c][r] * acc[m][c][r];
                q += __shfl_xor(q, 1, 64);
                q += __shfl_xor(q, 2, 64);
                q += __shfl_xor(q, 4, 64);
                q += __shfl_xor(q, 8, 64);
                if (lr == 0) rssW[wave][m * 16 + quad * 4 + r] = q;
            }
        __syncthreads();
        if (tid < 128) {
            float t = 0.f;
            #pragma unroll
            for (int w = 0; w < 8; ++w) t += rssW[w][tid];
            scaleL[tid] = rsqrtf(t * (1.0f / 512.0f) + 1e-6f);
        }
        __syncthreads();

        // ---- phase 4: h2 = x*scale*g2 -> LDS tile (same swizzled byte mapping) ----
        float g2v[4];
        #pragma unroll
        for (int c = 0; c < 4; ++c) g2v[c] = loadElem(g2, wave * 64 + c * 16 + lr, f);
        #pragma unroll
        for (int m = 0; m < 8; ++m)
            #pragma unroll
            for (int r = 0; r < 4; ++r) {
                const int row = m * 16 + quad * 4 + r;
                const float sc = scaleL[row];
                #pragma unroll
                for (int c = 0; c < 4; ++c) {
                    const int col = wave * 64 + c * 16 + lr;
                    const int byte_ = row * 1024 + (((col >> 3) ^ (row & 7)) << 4) + (col & 7) * 2;
                    *(unsigned short*)(L + byte_) = f2us(acc[m][c][r] * sc * g2v[c]);
                }
            }
    }
    __syncthreads();

    // ---- phase 5: FFN (exact ffn8 body; barrier-free) ----
    const __hip_bfloat16* pG = Bg + (size_t)(wave * 256 + lr) * 512 + quad * 8;
    const __hip_bfloat16* pU = Bu + (size_t)(wave * 256 + lr) * 512 + quad * 8;

    for (int ci = 0; ci < 8; ++ci) {
        const __hip_bfloat16* pGc = pG + (size_t)ci * 32 * 512;
        const __hip_bfloat16* pUc = pU + (size_t)ci * 32 * 512;

        f32x4 aG[8][2], aU[8][2];
        #pragma unroll
        for (int m = 0; m < 8; ++m)
            #pragma unroll
            for (int c = 0; c < 2; ++c)
                #pragma unroll
                for (int r = 0; r < 4; ++r) { aG[m][c][r] = 0.0f; aU[m][c][r] = 0.0f; }

        #pragma unroll 2
        for (int ks = 0; ks < 16; ++ks) {
            const int so = ((ks << 6) | (quad << 4)) ^ x7s;
            bf16x8 af[8];
            #pragma unroll
            for (int m = 0; m < 8; ++m)
                af[m] = *(const bf16x8*)(apq + m * 16384 + so);
            bf16x8 bg0 = *(const bf16x8*)(pGc + ks * 32);
            bf16x8 bg1 = *(const bf16x8*)(pGc + 16 * 512 + ks * 32);
            bf16x8 bu0 = *(const bf16x8*)(pUc + ks * 32);
            bf16x8 bu1 = *(const bf16x8*)(pUc + 16 * 512 + ks * 32);
            #pragma unroll
            for (int m = 0; m < 8; ++m) {
                aG[m][0] = __builtin_amdgcn_mfma_f32_16x16x32_bf16(af[m], bg0, aG[m][0], 0, 0, 0);
                aG[m][1] = __builtin_amdgcn_mfma_f32_16x16x32_bf16(af[m], bg1, aG[m][1], 0, 0, 0);
                aU[m][0] = __builtin_amdgcn_mfma_f32_16x16x32_bf16(af[m], bu0, aU[m][0], 0, 0, 0);
                aU[m][1] = __builtin_amdgcn_mfma_f32_16x16x32_bf16(af[m], bu1, aU[m][1], 0, 0, 0);
            }
        }

        #pragma unroll
        for (int c = 0; c < 2; ++c) {
            float s = 0.f;
            #pragma unroll
            for (int m = 0; m < 8; ++m)
                #pragma unroll
                for (int r = 0; r < 4; ++r) {
                    const float g = aG[m][c][r];
                    s += (g / (1.0f + expf(-g))) * aU[m][c][r];
                }
            s += __shfl_xor(s, 16, 64);
            s += __shfl_xor(s, 32, 64);
            if (quad == 0)
                atomicAdd(&tsum[b * 2048 + wave * 256 + ci * 32 + c * 16 + lr], s);
        }
    }
}

// ---------------- pooled[b][:] += tsum[b][:] @ Wd  (k-split parallel) ----------------
__global__ __launch_bounds__(256) void ffn_pool_kernel(
    const float* __restrict__ tsum, const void* __restrict__ Wd,
    float* __restrict__ pooled, const int* __restrict__ flag)
{
    __shared__ float ts[8][64];
    const int f = *flag;
    const int k0 = blockIdx.x * 64;
    const int t = threadIdx.x;
    for (int i = t; i < 512; i += 256)
        ts[i >> 6][i & 63] = tsum[(i >> 6) * 2048 + k0 + (i & 63)];
    __syncthreads();

    float acc0[8] = {}, acc1[8] = {};
    for (int kk = 0; kk < 64; ++kk) {
        const size_t krow = (size_t)(k0 + kk) * 512;
        const float w0 = loadElem(Wd, krow + t, f);
        const float w1 = loadElem(Wd, krow + t + 256, f);
        #pragma unroll
        for (int b = 0; b < 8; ++b) {
            acc0[b] += ts[b][kk] * w0;
            acc1[b] += ts[b][kk] * w1;
        }
    }
    #pragma unroll
    for (int b = 0; b < 8; ++b) {
        atomicAdd(&pooled[b * 512 + t], acc0[b]);
        atomicAdd(&pooled[b * 512 + t + 256], acc1[b]);
    }
}

// ---------------- kv / z global-state reduction (pkv [C][256] input) ----------------
__global__ __launch_bounds__(256) void kv_z_kernel(
    const __hip_bfloat16* __restrict__ pkv,
    float* __restrict__ kv, float* __restrict__ z, int gbase, int nrows)
{
    __shared__ float pks[8][64], vs[8][64];
    const int slab = blockIdx.x, kh = blockIdx.y;
    const int b = (gbase + slab * nrows) >> 13;
    const int tid = threadIdx.x;
    const int tm = (tid & 15) << 2, tdh = (tid >> 4) << 2;
    const int lss = tid >> 5, lmm = (tid & 31) << 1;

    float acc[4][4] = {};
    float zacc[4] = {};
    for (int sb = 0; sb < nrows; sb += 8) {
        __syncthreads();
        {
            const size_t n = (size_t)slab * nrows + sb + lss;
            const __hip_bfloat16* pr = pkv + n * 256 + kh * 64 + lmm;
            const __hip_bfloat16* vr = pkv + n * 256 + 128 + kh * 64 + lmm;
            pks[lss][lmm]     = bf2f(pr[0]);
            pks[lss][lmm + 1] = bf2f(pr[1]);
            vs[lss][lmm]      = bf2f(vr[0]);
            vs[lss][lmm + 1]  = bf2f(vr[1]);
        }
        __syncthreads();
        #pragma unroll
        for (int ss = 0; ss < 8; ++ss) {
            f32x4 p = *(const f32x4*)&pks[ss][tm];
            f32x4 w = *(const f32x4*)&vs[ss][tdh];
            #pragma unroll
            for (int i = 0; i < 4; ++i)
                #pragma unroll
                for (int j = 0; j < 4; ++j)
                    acc[i][j] += p[i] * w[j];
            if ((tid >> 4) == 0) {
                #pragma unroll
                for (int i = 0; i < 4; ++i) zacc[i] += p[i];
            }
        }
    }
    #pragma unroll
    for (int i = 0; i < 4; ++i)
        #pragma unroll
        for (int j = 0; j < 4; ++j)
            atomicAdd(&kv[(((size_t)b * 2 + kh) * 64 + tm + i) * 64 + tdh + j], acc[i][j]);
    if ((tid >> 4) == 0) {
        #pragma unroll
        for (int i = 0; i < 4; ++i)
            atomicAdd(&z[((size_t)b * 2 + kh) * 64 + tm + i], zacc[i]);
    }
}

// ---------------- classifier head ----------------
__global__ __launch_bounds__(256) void head_kernel(
    const float* __restrict__ pooled, const void* __restrict__ Wc,
    const void* __restrict__ bc, void* __restrict__ out, const int* __restrict__ flag)
{
    const int f = *flag;
    const int t = threadIdx.x;
    const int grp = t >> 4, ln = t & 15;
    const int b = grp >> 1, c = grp & 1;
    float p = 0.f;
    for (int d = ln; d < 512; d += 16)
        p += pooled[b * 512 + d] * loadElem(Wc, (size_t)d * 2 + c, f);
    #pragma unroll
    for (int off = 8; off; off >>= 1) p += __shfl_xor(p, off, 64);
    if (ln == 0) {
        const float val = p * (1.0f / 8192.0f) + loadElem(bc, c, f);
        if (f) ((float*)out)[b * 2 + c] = val;
        else   ((__hip_bfloat16*)out)[b * 2 + c] = f2bf(val);
    }
}

// ---------------- launch ----------------
extern "C" void kernel_launch(void* const* d_in, const int* in_sizes, int n_in,
                              void* d_out, int out_size, void* d_ws, size_t ws_size,
                              hipStream_t stream)
{
    const int* ids   = (const int*)d_in[0];
    const void* emb  = d_in[1];
    const void* Wq   = d_in[2];
    const void* Wk   = d_in[3];
    const void* Wv   = d_in[4];
    const void* Wph  = d_in[5];
    const void* Wo   = d_in[6];
    const void* g1   = d_in[7];
    const void* g2   = d_in[8];
    const void* Wg   = d_in[9];
    const void* Wu   = d_in[10];
    const void* Wd   = d_in[11];
    const void* Wc   = d_in[12];
    const void* bc   = d_in[13];

    char* ws = (char*)d_ws;
    __hip_bfloat16* WQPt  = (__hip_bfloat16*)(ws + OFF_WQPT);
    __hip_bfloat16* WKPt  = (__hip_bfloat16*)(ws + OFF_WKPT);  // [WKPt|WvT] = [256][512]
    __hip_bfloat16* WvT   = (__hip_bfloat16*)(ws + OFF_WVT);
    __hip_bfloat16* WoT   = (__hip_bfloat16*)(ws + OFF_WOT);
    __hip_bfloat16* WgT   = (__hip_bfloat16*)(ws + OFF_WGT);
    __hip_bfloat16* WuT   = (__hip_bfloat16*)(ws + OFF_WUT);
    float*          kv    = (float*)(ws + OFF_KV);
    float*          z     = (float*)(ws + OFF_Z);
    float*          pooled= (float*)(ws + OFF_POOL);
    float*          tsum  = (float*)(ws + OFF_TSUM);
    int*            flag  = (int*)(ws + OFF_FLAG);
    __hip_bfloat16* hall  = (__hip_bfloat16*)(ws + OFF_H);     // bf16 [65536][512], persistent

    // ---- adaptive chunk: largest power-of-2 C in [256, 65536] that fits ws ----
    // PERTOK=1536 (xf eliminated): C=65536 needs ~170 MB total -> NC=1 on proven ws.
    int C = 65536;
    while (C > 256 && CHUNKBASE + PERTOK * (size_t)C > ws_size) C >>= 1;
    const int NC = NTOK / C;

    char* cb = ws + CHUNKBASE;
    __hip_bfloat16* attn = (__hip_bfloat16*)cb;                         // bf16 [C][512]
    __hip_bfloat16* pkv  = (__hip_bfloat16*)(cb + (size_t)C * 1024);    // bf16 [C][256]

    detect_kernel<<<1, 128, 0, stream>>>((const unsigned int*)Wph, flag);
    zero_kernel<<<(ZERO_FLOATS + 255) / 256, 256, 0, stream>>>(kv, ZERO_FLOATS);

    // weight prep
    fuse_phi_kernel<<<1024, 256, 0, stream>>>(Wq, Wph, WQPt, 512, flag);
    fuse_phi_kernel<<<256, 256, 0, stream>>>(Wk, Wph, WKPt, 128, flag);
    transpose_kernel<<<dim3(128 / 32, 512 / 32), 256, 0, stream>>>(Wv, WvT, 512, 128, flag);
    transpose_kernel<<<dim3(512 / 32, 512 / 32), 256, 0, stream>>>(Wo, WoT, 512, 512, flag);
    transpose_kernel<<<dim3(2048 / 32, 512 / 32), 256, 0, stream>>>(Wg, WgT, 512, 2048, flag);
    transpose_kernel<<<dim3(2048 / 32, 512 / 32), 256, 0, stream>>>(Wu, WuT, 512, 2048, flag);

    // ---- pass A: per chunk h -> pk|v -> accumulate global kv / z ----
    for (int c = 0; c < NC; ++c) {
        const int g0 = c * C;
        __hip_bfloat16* hc = hall + (size_t)g0 * 512;
        embed_rms_kernel<<<C / 4, 256, 0, stream>>>(ids + g0, emb, g1, hc, flag);
        gemm128_kernel<8><<<dim3(C / 128, 2), 256, 0, stream>>>(
            hc, WKPt, pkv, flag, g0, 512);
        kv_z_kernel<<<dim3(C / 128, 2), 256, 0, stream>>>(pkv, kv, z, g0, 128);
    }

    // ---- pass B: per chunk (stored h) -> pq+mix -> fused Wo+residual+pool+rms+FFN ----
    for (int c = 0; c < NC; ++c) {
        const int g0 = c * C;
        __hip_bfloat16* hc = hall + (size_t)g0 * 512;
        pq_mix_kernel<<<dim3(C / 128, 4), 256, 0, stream>>>(
            hc, WQPt, kv, z, attn, g0, 512);
        wo_ffn_kernel<<<C / 128, 512, 0, stream>>>(
            attn, WoT, WgT, WuT, ids + g0, emb, g2, pooled, tsum, flag, g0);
    }

    // pooled += tsum @ Wd  (exact: pooling is linear; k-split parallel)
    ffn_pool_kernel<<<32, 256, 0, stream>>>(tsum, Wd, pooled, flag);

    head_kernel<<<1, 256, 0, stream>>>(pooled, Wc, bc, d_out, flag);
}